// Round 10
// baseline (1253.121 us; speedup 1.0000x reference)
//
#include <hip/hip_runtime.h>

// Decoder: B=16, T=128, V=32000, E=512, H=1024 (2 LSTM layers), CTX=2048.
// R10: short-critical-path persistent decoder.
//   - L0 input projection FULLY precomputed: cp (ctx, prep_ctx) + pe (emb,
//     pe_gemm MFMA). Hot loop does only hh0 / ih1 / hh1 GEMMs.
//   - All LDS in MFMA FRAGMENT ORDER: frag f at base+f*stride, lane l reads
//     base+l*16B -> conflict-free ds_read_b128 (R9 had 5.2e7 bank conflicts
//     from [row][col] layouts with stride=4 dwords mod 32).
//   - Per step: prefetch regs -> stage x(32K)+h1(32K) -> 1 sync -> 6 waves
//     run 16-MFMA bursts in parallel (hh1-k1 weights in wave5 REGISTERS;
//     LDS full at 155KB) -> gls partials -> 1 sync -> epilogue -> barrier.
//     2 syncthreads/step (was 6), 16-deep MFMA chain (was 5 serial phases).
// fc_gemm_mfma unchanged (~125us).

#define NBLK 256

typedef float f32x4 __attribute__((ext_vector_type(4)));
typedef __bf16 bf16x8 __attribute__((ext_vector_type(8)));
typedef unsigned short u16;

__device__ __forceinline__ float sigf(float x) { return 1.0f / (1.0f + __expf(-x)); }
__device__ __forceinline__ float tanh_(float x) {
  x = fminf(15.0f, fmaxf(-15.0f, x));
  float e = __expf(2.0f * x);
  return (e - 1.0f) / (e + 1.0f);
}

__device__ __forceinline__ u16 f2bf(float f) {
  __bf16 h = (__bf16)f;  // RNE
  return __builtin_bit_cast(u16, h);
}

__device__ __forceinline__ bf16x8 cvt8(float4 a, float4 b) {
  bf16x8 v;
  v[0] = (__bf16)a.x; v[1] = (__bf16)a.y; v[2] = (__bf16)a.z; v[3] = (__bf16)a.w;
  v[4] = (__bf16)b.x; v[5] = (__bf16)b.y; v[6] = (__bf16)b.z; v[7] = (__bf16)b.w;
  return v;
}

// Coherent (write-through) bf16 store.
__device__ __forceinline__ void st_cv16(u16* p, u16 v) {
  unsigned vv = v;
  asm volatile("global_store_short %0, %1, off sc0 sc1" :: "v"(p), "v"(vv) : "memory");
}

// Flag publish: drain own data stores, then plain sc0/sc1 flag store.
__device__ __forceinline__ void flag_store(unsigned* p, unsigned v) {
  asm volatile(
      "s_waitcnt vmcnt(0)\n\t"
      "global_store_dword %0, %1, off sc0 sc1"
      :: "v"(p), "v"(v) : "memory");
}

// 4 bypass flag loads in flight (no atomic lowering -> no buffer_inv).
__device__ __forceinline__ void ld4_flags(const unsigned* p, unsigned& a, unsigned& b,
                                          unsigned& c, unsigned& d) {
  asm volatile(
      "global_load_dword %0, %4, off sc0 sc1\n\t"
      "global_load_dword %1, %5, off sc0 sc1\n\t"
      "global_load_dword %2, %6, off sc0 sc1\n\t"
      "global_load_dword %3, %7, off sc0 sc1\n\t"
      "s_waitcnt vmcnt(0)"
      : "=&v"(a), "=&v"(b), "=&v"(c), "=&v"(d)
      : "v"(p), "v"(p + 16), "v"(p + 32), "v"(p + 48)
      : "memory");
}

// Flat one-hop pure-asm barrier: block's wave0 publishes flag, polls all 256.
__device__ __forceinline__ void gsyncf(unsigned step, unsigned* bar) {
  __syncthreads();
  const int tid = threadIdx.x;
  if (tid == 0) flag_store(bar + 16 + blockIdx.x * 16, step);
  if (tid < 64) {
    const unsigned* base = bar + 16 + tid * 64;  // 4 flags per lane
    for (;;) {
      unsigned a, b, c, d;
      ld4_flags(base, a, b, c, d);
      bool mine = (a >= step) & (b >= step) & (c >= step) & (d >= step);
      if (__all(mine)) break;
      __builtin_amdgcn_s_sleep(1);
    }
    asm volatile("" ::: "memory");
  }
  __syncthreads();
}

__device__ __forceinline__ void dot4(float& a, float4 wv, float4 xv) {
  a = fmaf(wv.x, xv.x, a);
  a = fmaf(wv.y, xv.y, a);
  a = fmaf(wv.z, xv.z, a);
  a = fmaf(wv.w, xv.w, a);
}

// ---- prep: gather token embeddings as bf16: x0b[tb][512], tb = t*16+b ----
__global__ void prep_emb(const int* __restrict__ tgt, const float* __restrict__ emb,
                         u16* __restrict__ x0b) {
  const int g = blockIdx.x * blockDim.x + threadIdx.x;  // 131072 total
  const int col8 = (g & 63) * 8;
  const int tb = g >> 6;            // 0..2047
  const int t = tb >> 4, b = tb & 15;
  const int tok = (t == 0) ? 1 : tgt[b * 128 + (t - 1)];
  const float* s = emb + (size_t)tok * 512 + col8;
  float4 a = *(const float4*)s;
  float4 bb = *(const float4*)(s + 4);
  __align__(16) u16 r[8] = {f2bf(a.x), f2bf(a.y), f2bf(a.z), f2bf(a.w),
                            f2bf(bb.x), f2bf(bb.y), f2bf(bb.z), f2bf(bb.w)};
  *(uint4*)(x0b + (size_t)tb * 512 + col8) = *(uint4*)r;
}

// ---- prep: fp32 ctx projection cp[j][b] = sum_k wih0[j][512+k]*ctx[b][k] ----
__global__ __launch_bounds__(256, 1) void prep_ctx(const float* __restrict__ enc_h,
                                                   const float* __restrict__ wih0,
                                                   float* __restrict__ cp) {
  __shared__ float ctx[16][2052];
  const int tid = threadIdx.x;
#pragma unroll
  for (int c = 0; c < 32; ++c) {
    int f4 = tid + c * 256;
    int b = f4 >> 9, kq = f4 & 511;
    *(float4*)&ctx[b][kq * 4] =
        *(const float4*)(enc_h + (kq >> 7) * 8192 + b * 512 + (kq & 127) * 4);
  }
  __syncthreads();
  const int jr = tid >> 4, b = tid & 15;
  const int j = blockIdx.x * 16 + jr;
  const float* w = wih0 + (size_t)j * 2560 + 512;
  float a0 = 0.f, a1 = 0.f, a2 = 0.f, a3 = 0.f;
  for (int k = 0; k < 2048; k += 16) {
    float4 w0 = *(const float4*)(w + k);
    float4 w1 = *(const float4*)(w + k + 4);
    float4 w2 = *(const float4*)(w + k + 8);
    float4 w3 = *(const float4*)(w + k + 12);
    float4 x0 = *(const float4*)&ctx[b][k];
    float4 x1 = *(const float4*)&ctx[b][k + 4];
    float4 x2 = *(const float4*)&ctx[b][k + 8];
    float4 x3 = *(const float4*)&ctx[b][k + 12];
    dot4(a0, w0, x0); dot4(a1, w1, x1); dot4(a2, w2, x2); dot4(a3, w3, x3);
  }
  cp[(size_t)j * 16 + b] = a0 + a1 + a2 + a3;
}

// ---- prep: pe[tb][j] = sum_k x0b[tb][k] * wih0[j][k], k<512 (emb cols) ----
__global__ __launch_bounds__(256, 2) void pe_gemm(
    const u16* __restrict__ A, const float* __restrict__ Bw, float* __restrict__ C) {
  __shared__ __align__(16) u16 Al[128][40];
  __shared__ __align__(16) u16 Bl[128][40];
  const int tid = threadIdx.x;
  const int m0 = blockIdx.x * 128;   // 16 m-tiles (tb)
  const int n0 = blockIdx.y * 128;   // 32 n-tiles (j)
  const int wave = tid >> 6;
  const int lane = tid & 63;
  const int wm = (wave & 1) * 64;
  const int wn = (wave >> 1) * 64;
  const int fr = lane & 15;
  const int ks = lane >> 4;
  const int srow = tid >> 1;
  const int sh16 = (tid & 1) * 16;
  const u16* Ag = A + (size_t)(m0 + srow) * 512 + sh16;
  const float* Bg = Bw + (size_t)(n0 + srow) * 2560 + sh16;
  f32x4 acc[4][4] = {};
  for (int k0 = 0; k0 < 512; k0 += 32) {
    uint4 a0 = *(const uint4*)(Ag + k0);
    uint4 a1 = *(const uint4*)(Ag + k0 + 8);
    float bfv[16];
    *(float4*)&bfv[0] = *(const float4*)(Bg + k0);
    *(float4*)&bfv[4] = *(const float4*)(Bg + k0 + 4);
    *(float4*)&bfv[8] = *(const float4*)(Bg + k0 + 8);
    *(float4*)&bfv[12] = *(const float4*)(Bg + k0 + 12);
    u16 bu[16];
#pragma unroll
    for (int u = 0; u < 16; ++u) bu[u] = f2bf(bfv[u]);
    __syncthreads();
    *(uint4*)&Al[srow][sh16] = a0;
    *(uint4*)&Al[srow][sh16 + 8] = a1;
    *(uint4*)&Bl[srow][sh16] = *(uint4*)&bu[0];
    *(uint4*)&Bl[srow][sh16 + 8] = *(uint4*)&bu[8];
    __syncthreads();
    bf16x8 af[4], bf[4];
#pragma unroll
    for (int i = 0; i < 4; ++i) af[i] = *(const bf16x8*)&Al[wm + i * 16 + fr][ks * 8];
#pragma unroll
    for (int j = 0; j < 4; ++j) bf[j] = *(const bf16x8*)&Bl[wn + j * 16 + fr][ks * 8];
#pragma unroll
    for (int i = 0; i < 4; ++i)
#pragma unroll
      for (int j = 0; j < 4; ++j)
        acc[i][j] = __builtin_amdgcn_mfma_f32_16x16x32_bf16(af[i], bf[j], acc[i][j], 0, 0, 0);
  }
  const int mrb = (lane >> 4) * 4;
#pragma unroll
  for (int i = 0; i < 4; ++i) {
#pragma unroll
    for (int r = 0; r < 4; ++r) {
      const int m = m0 + wm + i * 16 + mrb + r;
      float* dst = C + (size_t)m * 4096;
#pragma unroll
      for (int j = 0; j < 4; ++j) dst[n0 + wn + j * 16 + fr] = acc[i][j][r];
    }
  }
}

// 16 chained MFMAs, LDS weights (fragment order, tight 512-u16 frags).
#define BURST_L(ACC, XB, XOFF, WF0)                                        \
  _Pragma("unroll")                                                        \
  for (int mm = 0; mm < 16; ++mm) {                                        \
    bf16x8 av = *(const bf16x8*)&XB[(XOFF) + mm * 520 + lane8];            \
    bf16x8 bv = *(const bf16x8*)&wf[((WF0) + mm) * 512 + lane8];           \
    ACC = __builtin_amdgcn_mfma_f32_16x16x32_bf16(av, bv, ACC, 0, 0, 0);   \
  }
// 16 chained MFMAs, register weights (wave5).
#define BURST_R(ACC, XB, XOFF)                                             \
  _Pragma("unroll")                                                        \
  for (int mm = 0; mm < 16; ++mm) {                                        \
    bf16x8 av = *(const bf16x8*)&XB[(XOFF) + mm * 520 + lane8];            \
    ACC = __builtin_amdgcn_mfma_f32_16x16x32_bf16(av, bw[mm], ACC, 0, 0, 0); \
  }

// ---------------- persistent MFMA decoder (short critical path) ----------
// Rings (bf16, write-once): xr slot t+1 = h0/x1[t] (slot 0 = init h0);
//                           h1r slot t+1 = h1[t] (slot 0 = init h1).
__global__ __launch_bounds__(512, 1) void dec_seq_mf2(
    const float* __restrict__ enc_h, const float* __restrict__ enc_c,
    const float* __restrict__ whh0, const float* __restrict__ wih1,
    const float* __restrict__ whh1,
    const float* __restrict__ bih0, const float* __restrict__ bhh0,
    const float* __restrict__ bih1, const float* __restrict__ bhh1,
    const float* __restrict__ cp, const float* __restrict__ pe,
    u16* __restrict__ xr, u16* __restrict__ h1r,
    u16* __restrict__ out2b, unsigned* bar) {
  __shared__ u16 xf[16640];        // 32 frags * 520 (x slot s, K=1024)
  __shared__ u16 h1f[16640];       // 32 frags * 520 (h1 slot s-1)
  __shared__ u16 wf[40960];        // 5 weight chunks * 16 frags * 512 (tight)
  __shared__ float gls[6][16][17]; // partial acc tiles [wave][p][batch]

  const int tid = threadIdx.x;
  const int wgid = blockIdx.x;
  const int w4 = wgid * 4;
  const int lane = tid & 63;
  const int wave = tid >> 6;
  const int lane8 = lane * 8;
  unsigned step = 0;

  // ---- INIT: weight fragments -> LDS (chunks: hh0k0,hh0k1,ih1k0,ih1k1,hh1k0)
  for (int it = 0; it < 10; ++it) {
    const int slot = tid + it * 512;      // 0..5119
    const int fg = slot >> 6;             // frag 0..79
    const int l = slot & 63;
    const int ch = fg >> 4, mm = fg & 15;
    const int nn = l & 15;
    const int j = (nn >> 2) * 1024 + w4 + (nn & 3);
    const int k = ((ch == 1 || ch == 3) ? 512 : 0) + mm * 32 + ((l >> 4) * 8);
    const float* src = (ch < 2) ? whh0 : (ch < 4) ? wih1 : whh1;
    const float* s = src + (size_t)j * 1024 + k;
    float4 a = *(const float4*)s;
    float4 b = *(const float4*)(s + 4);
    bf16x8 v = cvt8(a, b);
    *(uint4*)&wf[fg * 512 + l * 8] = __builtin_bit_cast(uint4, v);
  }
  // wave5 private: whh1 k=512..1023 fragments in registers
  bf16x8 bw[16];
  if (wave == 5) {
    const int nn = lane & 15;
    const int j = (nn >> 2) * 1024 + w4 + (nn & 3);
#pragma unroll
    for (int mm = 0; mm < 16; ++mm) {
      const float* s = whh1 + (size_t)j * 1024 + 512 + mm * 32 + (lane >> 4) * 8;
      bw[mm] = cvt8(*(const float4*)s, *(const float4*)(s + 4));
    }
  }

  // ---- INIT per-thread gate state (tid<64: unit gdj, batch gb) ----
  const int gdj = tid >> 4;
  const int gb = tid & 15;
  float cpA0 = 0.f, cpA1 = 0.f, cpA2 = 0.f, cpA3 = 0.f;
  float cpB0 = 0.f, cpB1 = 0.f, cpB2 = 0.f, cpB3 = 0.f;
  float c0r = 0.f, c1r = 0.f;
  if (tid < 64) {
    const int jp = w4 + gdj;
    cpA0 = cp[(size_t)(jp) * 16 + gb] + bih0[jp] + bhh0[jp];
    cpA1 = cp[(size_t)(1024 + jp) * 16 + gb] + bih0[1024 + jp] + bhh0[1024 + jp];
    cpA2 = cp[(size_t)(2048 + jp) * 16 + gb] + bih0[2048 + jp] + bhh0[2048 + jp];
    cpA3 = cp[(size_t)(3072 + jp) * 16 + gb] + bih0[3072 + jp] + bhh0[3072 + jp];
    cpB0 = bih1[jp] + bhh1[jp];
    cpB1 = bih1[1024 + jp] + bhh1[1024 + jp];
    cpB2 = bih1[2048 + jp] + bhh1[2048 + jp];
    cpB3 = bih1[3072 + jp] + bhh1[3072 + jp];
    const int dir = jp >> 9, e = jp & 511;
    c0r = enc_c[dir * 8192 + gb * 512 + e];
    c1r = enc_c[(2 + dir) * 8192 + gb * 512 + e];
    st_cv16(xr + gb * 1024 + jp, f2bf(enc_h[dir * 8192 + gb * 512 + e]));
    st_cv16(h1r + gb * 1024 + jp, f2bf(enc_h[(2 + dir) * 8192 + gb * 512 + e]));
  }
  gsyncf(++step, bar);

  // staging coords: thread covers row sm, k = sk0 + j*256 (4 uint4s per buf)
  const int sm = tid >> 5;
  const int sk0 = (tid & 31) * 8;

  // ---- MAIN LOOP: 129 macro-steps; A = L0[t=s], B = L1[t=s-1] ----
  for (int s = 0; s < 129; ++s) {
    const bool doA = (s < 128), doB = (s >= 1);
    // prefetch ring slabs + pe row (plain cached; rings write-once)
    uint4 rx[4], rh[4] = {};
    float pe0 = 0.f, pe1 = 0.f, pe2 = 0.f, pe3 = 0.f;
    {
      const u16* sx = xr + (size_t)s * 16384 + sm * 1024;
#pragma unroll
      for (int jj = 0; jj < 4; ++jj) rx[jj] = *(const uint4*)(sx + sk0 + jj * 256);
      if (doB) {
        const u16* sh = h1r + (size_t)(s - 1) * 16384 + sm * 1024;
#pragma unroll
        for (int jj = 0; jj < 4; ++jj) rh[jj] = *(const uint4*)(sh + sk0 + jj * 256);
      }
      if (doA && tid < 64) {
        const float* pp = pe + (size_t)(s * 16 + gb) * 4096 + (w4 + gdj);
        pe0 = pp[0]; pe1 = pp[1024]; pe2 = pp[2048]; pe3 = pp[3072];
      }
    }
    // stage to fragment-order LDS
#pragma unroll
    for (int jj = 0; jj < 4; ++jj) {
      const int k = sk0 + jj * 256;
      const int f = k >> 5;
      const int lt = sm + 16 * ((k >> 3) & 3);
      *(uint4*)&xf[f * 520 + lt * 8] = rx[jj];
    }
    if (doB) {
#pragma unroll
      for (int jj = 0; jj < 4; ++jj) {
        const int k = sk0 + jj * 256;
        const int f = k >> 5;
        const int lt = sm + 16 * ((k >> 3) & 3);
        *(uint4*)&h1f[f * 520 + lt * 8] = rh[jj];
      }
    }
    __syncthreads();

    // 6 parallel 16-MFMA bursts
    f32x4 acc = {0.f, 0.f, 0.f, 0.f};
    if (wave == 0 && doA) { BURST_L(acc, xf, 0, 0) }        // hh0 k0..511
    if (wave == 1 && doA) { BURST_L(acc, xf, 8320, 16) }    // hh0 k512..1023
    if (wave == 2 && doB) { BURST_L(acc, xf, 0, 32) }       // ih1 k0..511
    if (wave == 3 && doB) { BURST_L(acc, xf, 8320, 48) }    // ih1 k512..1023
    if (wave == 4 && doB) { BURST_L(acc, h1f, 0, 64) }      // hh1 k0..511
    if (wave == 5 && doB) { BURST_R(acc, h1f, 8320) }       // hh1 k512..1023
    if ((wave <= 1 && doA) || (wave >= 2 && wave <= 5 && doB)) {
#pragma unroll
      for (int r = 0; r < 4; ++r) gls[wave][lane & 15][(lane >> 4) * 4 + r] = acc[r];
    }
    __syncthreads();

    // epilogue: gate math + ring stores (wave0)
    if (tid < 64) {
      const int jp = w4 + gdj;
      if (doA) {
        float gi = gls[0][gdj][gb] + gls[1][gdj][gb] + pe0 + cpA0;
        float gf = gls[0][4 + gdj][gb] + gls[1][4 + gdj][gb] + pe1 + cpA1;
        float gg = gls[0][8 + gdj][gb] + gls[1][8 + gdj][gb] + pe2 + cpA2;
        float go = gls[0][12 + gdj][gb] + gls[1][12 + gdj][gb] + pe3 + cpA3;
        c0r = sigf(gf) * c0r + sigf(gi) * tanh_(gg);
        float h = sigf(go) * tanh_(c0r);
        st_cv16(xr + (size_t)(s + 1) * 16384 + gb * 1024 + jp, f2bf(h));
      }
      if (doB) {
        float gi = gls[2][gdj][gb] + gls[3][gdj][gb] + gls[4][gdj][gb] +
                   gls[5][gdj][gb] + cpB0;
        float gf = gls[2][4 + gdj][gb] + gls[3][4 + gdj][gb] + gls[4][4 + gdj][gb] +
                   gls[5][4 + gdj][gb] + cpB1;
        float gg = gls[2][8 + gdj][gb] + gls[3][8 + gdj][gb] + gls[4][8 + gdj][gb] +
                   gls[5][8 + gdj][gb] + cpB2;
        float go = gls[2][12 + gdj][gb] + gls[3][12 + gdj][gb] + gls[4][12 + gdj][gb] +
                   gls[5][12 + gdj][gb] + cpB3;
        c1r = sigf(gf) * c1r + sigf(gi) * tanh_(gg);
        float h = sigf(go) * tanh_(c1r);
        st_cv16(h1r + (size_t)s * 16384 + gb * 1024 + jp, f2bf(h));
        out2b[((s - 1) * 16 + gb) * 1024 + jp] = f2bf(tanh_(h));
      }
    }
    gsyncf(++step, bar);
  }
}

// logits GEMM: A bf16 [2048][1024]; B fp32 [32000][1024] (cvt per tile); C fp32.
__global__ __launch_bounds__(256, 2) void fc_gemm_mfma(
    const u16* __restrict__ A, const float* __restrict__ Bw,
    const float* __restrict__ bias, float* __restrict__ C) {
  __shared__ __align__(16) u16 Al[128][40];
  __shared__ __align__(16) u16 Bl[128][40];

  const int tid = threadIdx.x;
  const int m0 = blockIdx.x * 128;
  const int n0 = blockIdx.y * 128;
  const int wave = tid >> 6;
  const int lane = tid & 63;
  const int wm = (wave & 1) * 64;
  const int wn = (wave >> 1) * 64;
  const int fr = lane & 15;
  const int ks = lane >> 4;

  const int srow = tid >> 1;
  const int sh16 = (tid & 1) * 16;

  const u16* Ag = A + (size_t)(m0 + srow) * 1024 + sh16;
  const float* Bg = Bw + (size_t)(n0 + srow) * 1024 + sh16;

  f32x4 acc[4][4] = {};

  for (int k0 = 0; k0 < 1024; k0 += 32) {
    uint4 a0 = *(const uint4*)(Ag + k0);
    uint4 a1 = *(const uint4*)(Ag + k0 + 8);
    float bfv[16];
    *(float4*)&bfv[0] = *(const float4*)(Bg + k0);
    *(float4*)&bfv[4] = *(const float4*)(Bg + k0 + 4);
    *(float4*)&bfv[8] = *(const float4*)(Bg + k0 + 8);
    *(float4*)&bfv[12] = *(const float4*)(Bg + k0 + 12);
    u16 bu[16];
#pragma unroll
    for (int u = 0; u < 16; ++u) bu[u] = f2bf(bfv[u]);

    __syncthreads();
    *(uint4*)&Al[srow][sh16] = a0;
    *(uint4*)&Al[srow][sh16 + 8] = a1;
    *(uint4*)&Bl[srow][sh16] = *(uint4*)&bu[0];
    *(uint4*)&Bl[srow][sh16 + 8] = *(uint4*)&bu[8];
    __syncthreads();

    bf16x8 af[4], bf[4];
#pragma unroll
    for (int i = 0; i < 4; ++i) af[i] = *(const bf16x8*)&Al[wm + i * 16 + fr][ks * 8];
#pragma unroll
    for (int j = 0; j < 4; ++j) bf[j] = *(const bf16x8*)&Bl[wn + j * 16 + fr][ks * 8];
#pragma unroll
    for (int i = 0; i < 4; ++i)
#pragma unroll
      for (int j = 0; j < 4; ++j)
        acc[i][j] = __builtin_amdgcn_mfma_f32_16x16x32_bf16(af[i], bf[j], acc[i][j], 0, 0, 0);
  }

  float bj[4];
#pragma unroll
  for (int j = 0; j < 4; ++j) bj[j] = bias[n0 + wn + j * 16 + fr];

  const int mrb = (lane >> 4) * 4;
#pragma unroll
  for (int i = 0; i < 4; ++i) {
#pragma unroll
    for (int r = 0; r < 4; ++r) {
      const int m = m0 + wm + i * 16 + mrb + r;
      float* dst = C + ((size_t)(m & 15) * 128 + (m >> 4)) * 32000;
#pragma unroll
      for (int j = 0; j < 4; ++j) {
        dst[n0 + wn + j * 16 + fr] = acc[i][j][r] + bj[j];
      }
    }
  }
}

extern "C" void kernel_launch(void* const* d_in, const int* in_sizes, int n_in,
                              void* d_out, int out_size, void* d_ws, size_t ws_size,
                              hipStream_t stream) {
  const float* enc_h = (const float*)d_in[0];
  const float* enc_c = (const float*)d_in[1];
  const int* tgt = (const int*)d_in[2];
  const float* emb = (const float*)d_in[3];
  const float* wih0 = (const float*)d_in[4];
  const float* whh0 = (const float*)d_in[5];
  const float* bih0 = (const float*)d_in[6];
  const float* bhh0 = (const float*)d_in[7];
  const float* wih1 = (const float*)d_in[8];
  const float* whh1 = (const float*)d_in[9];
  const float* bih1 = (const float*)d_in[10];
  const float* bhh1 = (const float*)d_in[11];
  const float* fcw = (const float*)d_in[12];
  const float* fcb = (const float*)d_in[13];
  float* logits = (float*)d_out;

  unsigned* bar = (unsigned*)d_ws;  // 32 KB barrier region
  hipMemsetAsync(d_ws, 0, 64 + 256 * 64, stream);

  // ws layout (~48.6 MB):
  float* cp = (float*)((char*)d_ws + 32768);  // 4096*16 f32       = 256 KB
  u16* x0b = (u16*)(cp + 65536);              // 2048*512 bf16     = 2 MB
  float* pe = (float*)(x0b + 1048576);        // 2048*4096 f32     = 33.5 MB
  u16* xr = (u16*)(pe + 8388608);             // 129*16384 bf16    = 4.125 MB
  u16* h1r = xr + 2113536;                    // 129*16384 bf16    = 4.125 MB
  u16* out2b = h1r + 2113536;                 // 2048*1024 bf16    = 4 MB

  prep_emb<<<512, 256, 0, stream>>>(tgt, emb, x0b);
  prep_ctx<<<256, 256, 0, stream>>>(enc_h, wih0, cp);
  pe_gemm<<<dim3(16, 32), 256, 0, stream>>>(x0b, wih0, pe);
  dec_seq_mf2<<<NBLK, 512, 0, stream>>>(enc_h, enc_c, whh0, wih1, whh1,
                                        bih0, bhh0, bih1, bhh1, cp, pe,
                                        xr, h1r, out2b, bar);
  fc_gemm_mfma<<<dim3(16, 250), 256, 0, stream>>>(out2b, fcw, fcb, logits);
}

// Round 11
// 1080.888 us; speedup vs baseline: 1.1593x; 1.1593x over previous
//
#include <hip/hip_runtime.h>

// Decoder: B=16, T=128, V=32000, E=512, H=1024 (2 LSTM layers), CTX=2048.
// R11: register-resident weights + single-phase wave-parallel recurrence.
//   - Each of 7 compute waves holds its 16 MFMA weight fragments in VGPRs
//     (bw[16], loaded+converted once at INIT). No per-step weight reads at
//     all (LDS or global). LDS only holds x slabs (88 KB).
//   - Per step: prefetch ring slabs -> contiguous staging writes -> 1 sync ->
//     7 parallel 16-MFMA bursts (w0 emb, w1/w2 hh0 | w3/w4 ih1, w5/w6 hh1)
//     -> gls partials -> 1 sync -> epilogue -> flat asm grid barrier.
//   - R10 post-mortem: pe precompute (scattered cold reads) and 4-way staging
//     write conflicts caused the regression; both removed. R9-style slab
//     layouts ([m][k], strides 520/1032 u16) keep reads balanced and writes
//     contiguous.
// fc_gemm_mfma: bf16 MFMA GEMM -> [16][128][32000] logits (~125us).

#define NBLK 256

typedef float f32x4 __attribute__((ext_vector_type(4)));
typedef __bf16 bf16x8 __attribute__((ext_vector_type(8)));
typedef unsigned short u16;

__device__ __forceinline__ float sigf(float x) { return 1.0f / (1.0f + __expf(-x)); }
__device__ __forceinline__ float tanh_(float x) {
  x = fminf(15.0f, fmaxf(-15.0f, x));
  float e = __expf(2.0f * x);
  return (e - 1.0f) / (e + 1.0f);
}

__device__ __forceinline__ u16 f2bf(float f) {
  __bf16 h = (__bf16)f;  // RNE
  return __builtin_bit_cast(u16, h);
}

__device__ __forceinline__ bf16x8 cvt8(float4 a, float4 b) {
  bf16x8 v;
  v[0] = (__bf16)a.x; v[1] = (__bf16)a.y; v[2] = (__bf16)a.z; v[3] = (__bf16)a.w;
  v[4] = (__bf16)b.x; v[5] = (__bf16)b.y; v[6] = (__bf16)b.z; v[7] = (__bf16)b.w;
  return v;
}

// Coherent (write-through) bf16 store.
__device__ __forceinline__ void st_cv16(u16* p, u16 v) {
  unsigned vv = v;
  asm volatile("global_store_short %0, %1, off sc0 sc1" :: "v"(p), "v"(vv) : "memory");
}

// Flag publish: drain own data stores, then plain sc0/sc1 flag store.
__device__ __forceinline__ void flag_store(unsigned* p, unsigned v) {
  asm volatile(
      "s_waitcnt vmcnt(0)\n\t"
      "global_store_dword %0, %1, off sc0 sc1"
      :: "v"(p), "v"(v) : "memory");
}

// 4 bypass flag loads in flight (no atomic lowering -> no buffer_inv).
__device__ __forceinline__ void ld4_flags(const unsigned* p, unsigned& a, unsigned& b,
                                          unsigned& c, unsigned& d) {
  asm volatile(
      "global_load_dword %0, %4, off sc0 sc1\n\t"
      "global_load_dword %1, %5, off sc0 sc1\n\t"
      "global_load_dword %2, %6, off sc0 sc1\n\t"
      "global_load_dword %3, %7, off sc0 sc1\n\t"
      "s_waitcnt vmcnt(0)"
      : "=&v"(a), "=&v"(b), "=&v"(c), "=&v"(d)
      : "v"(p), "v"(p + 16), "v"(p + 32), "v"(p + 48)
      : "memory");
}

// Flat one-hop pure-asm barrier: block's wave0 publishes flag, polls all 256.
__device__ __forceinline__ void gsyncf(unsigned step, unsigned* bar) {
  __syncthreads();
  const int tid = threadIdx.x;
  if (tid == 0) flag_store(bar + 16 + blockIdx.x * 16, step);
  if (tid < 64) {
    const unsigned* base = bar + 16 + tid * 64;  // 4 flags per lane
    for (;;) {
      unsigned a, b, c, d;
      ld4_flags(base, a, b, c, d);
      bool mine = (a >= step) & (b >= step) & (c >= step) & (d >= step);
      if (__all(mine)) break;
      __builtin_amdgcn_s_sleep(1);
    }
    asm volatile("" ::: "memory");
  }
  __syncthreads();
}

__device__ __forceinline__ void dot4(float& a, float4 wv, float4 xv) {
  a = fmaf(wv.x, xv.x, a);
  a = fmaf(wv.y, xv.y, a);
  a = fmaf(wv.z, xv.z, a);
  a = fmaf(wv.w, xv.w, a);
}

// ---- prep: gather token embeddings as bf16: x0b[tb][512], tb = t*16+b ----
__global__ void prep_emb(const int* __restrict__ tgt, const float* __restrict__ emb,
                         u16* __restrict__ x0b) {
  const int g = blockIdx.x * blockDim.x + threadIdx.x;  // 131072 total
  const int col8 = (g & 63) * 8;
  const int tb = g >> 6;            // 0..2047
  const int t = tb >> 4, b = tb & 15;
  const int tok = (t == 0) ? 1 : tgt[b * 128 + (t - 1)];
  const float* s = emb + (size_t)tok * 512 + col8;
  float4 a = *(const float4*)s;
  float4 bb = *(const float4*)(s + 4);
  __align__(16) u16 r[8] = {f2bf(a.x), f2bf(a.y), f2bf(a.z), f2bf(a.w),
                            f2bf(bb.x), f2bf(bb.y), f2bf(bb.z), f2bf(bb.w)};
  *(uint4*)(x0b + (size_t)tb * 512 + col8) = *(uint4*)r;
}

// ---- prep: fp32 ctx projection cp[j][b] = sum_k wih0[j][512+k]*ctx[b][k] ----
__global__ __launch_bounds__(256, 1) void prep_ctx(const float* __restrict__ enc_h,
                                                   const float* __restrict__ wih0,
                                                   float* __restrict__ cp) {
  __shared__ float ctx[16][2052];
  const int tid = threadIdx.x;
#pragma unroll
  for (int c = 0; c < 32; ++c) {
    int f4 = tid + c * 256;
    int b = f4 >> 9, kq = f4 & 511;
    *(float4*)&ctx[b][kq * 4] =
        *(const float4*)(enc_h + (kq >> 7) * 8192 + b * 512 + (kq & 127) * 4);
  }
  __syncthreads();
  const int jr = tid >> 4, b = tid & 15;
  const int j = blockIdx.x * 16 + jr;
  const float* w = wih0 + (size_t)j * 2560 + 512;
  float a0 = 0.f, a1 = 0.f, a2 = 0.f, a3 = 0.f;
  for (int k = 0; k < 2048; k += 16) {
    float4 w0 = *(const float4*)(w + k);
    float4 w1 = *(const float4*)(w + k + 4);
    float4 w2 = *(const float4*)(w + k + 8);
    float4 w3 = *(const float4*)(w + k + 12);
    float4 x0 = *(const float4*)&ctx[b][k];
    float4 x1 = *(const float4*)&ctx[b][k + 4];
    float4 x2 = *(const float4*)&ctx[b][k + 8];
    float4 x3 = *(const float4*)&ctx[b][k + 12];
    dot4(a0, w0, x0); dot4(a1, w1, x1); dot4(a2, w2, x2); dot4(a3, w3, x3);
  }
  cp[(size_t)j * 16 + b] = a0 + a1 + a2 + a3;
}

// 16 chained MFMAs; A-frags from LDS slab BP (stride S u16, col off XOFF),
// B-frags from this wave's register weights bw[16].
#define BURST(ACC, BP, S, XOFF)                                              \
  _Pragma("unroll")                                                          \
  for (int mm = 0; mm < 16; ++mm) {                                          \
    bf16x8 av = *(const bf16x8*)&(BP)[fr * (S) + (XOFF) + mm * 32 + ks8];    \
    ACC = __builtin_amdgcn_mfma_f32_16x16x32_bf16(av, bw[mm], ACC, 0, 0, 0); \
  }

// ---------------- persistent MFMA decoder (register weights) -------------
// Rings (bf16, write-once): xr slot t+1 = h0/x1[t] (slot 0 = init h0);
//                           h1r slot t+1 = h1[t] (slot 0 = init h1).
__global__ __launch_bounds__(512, 1) void dec_seq_rw(
    const float* __restrict__ enc_h, const float* __restrict__ enc_c,
    const float* __restrict__ wih0, const float* __restrict__ whh0,
    const float* __restrict__ wih1, const float* __restrict__ whh1,
    const float* __restrict__ bih0, const float* __restrict__ bhh0,
    const float* __restrict__ bih1, const float* __restrict__ bhh1,
    const float* __restrict__ cp, const u16* __restrict__ x0b,
    u16* __restrict__ xr, u16* __restrict__ h1r,
    u16* __restrict__ out2b, unsigned* bar) {
  __shared__ u16 xe[16 * 520];      // emb slab   [m][k<512], stride 520
  __shared__ u16 xs[16 * 1032];     // x slot s   [m][k<1024], stride 1032
  __shared__ u16 h1s[16 * 1032];    // h1 slot s-1
  __shared__ float gls[7][16][17];  // partial acc tiles [wave][p][batch]

  const int tid = threadIdx.x;
  const int wgid = blockIdx.x;
  const int w4 = wgid * 4;
  const int lane = tid & 63;
  const int wave = tid >> 6;
  const int fr = lane & 15;
  const int ks8 = (lane >> 4) * 8;
  unsigned step = 0;

  // ---- INIT: this wave's 16 weight fragments -> registers (fp32->bf16) ----
  // wave0: wih0 emb cols; w1/w2: whh0 k0/k1; w3/w4: wih1 k0/k1; w5/w6: whh1.
  bf16x8 bw[16];
  {
    const int nn = lane & 15;
    const int j = (nn >> 2) * 1024 + w4 + (nn & 3);
    const float* wsrc = nullptr;
    size_t wstride = 1024;
    int wko = 0;
    if (wave == 0) { wsrc = wih0; wstride = 2560; wko = 0; }
    else if (wave == 1) { wsrc = whh0; wko = 0; }
    else if (wave == 2) { wsrc = whh0; wko = 512; }
    else if (wave == 3) { wsrc = wih1; wko = 0; }
    else if (wave == 4) { wsrc = wih1; wko = 512; }
    else if (wave == 5) { wsrc = whh1; wko = 0; }
    else if (wave == 6) { wsrc = whh1; wko = 512; }
    if (wsrc) {
      const float* base = wsrc + (size_t)j * wstride + wko + (lane >> 4) * 8;
#pragma unroll
      for (int mm = 0; mm < 16; ++mm) {
        const float* sp = base + mm * 32;
        bw[mm] = cvt8(*(const float4*)sp, *(const float4*)(sp + 4));
      }
    } else {
#pragma unroll
      for (int mm = 0; mm < 16; ++mm) bw[mm] = bf16x8{};
    }
  }

  // ---- INIT per-thread gate state (tid<64: unit gdj, batch gb) ----
  const int gdj = tid >> 4;
  const int gb = tid & 15;
  float cpA0 = 0.f, cpA1 = 0.f, cpA2 = 0.f, cpA3 = 0.f;
  float cpB0 = 0.f, cpB1 = 0.f, cpB2 = 0.f, cpB3 = 0.f;
  float c0r = 0.f, c1r = 0.f;
  if (tid < 64) {
    const int jp = w4 + gdj;
    cpA0 = cp[(size_t)(jp) * 16 + gb] + bih0[jp] + bhh0[jp];
    cpA1 = cp[(size_t)(1024 + jp) * 16 + gb] + bih0[1024 + jp] + bhh0[1024 + jp];
    cpA2 = cp[(size_t)(2048 + jp) * 16 + gb] + bih0[2048 + jp] + bhh0[2048 + jp];
    cpA3 = cp[(size_t)(3072 + jp) * 16 + gb] + bih0[3072 + jp] + bhh0[3072 + jp];
    cpB0 = bih1[jp] + bhh1[jp];
    cpB1 = bih1[1024 + jp] + bhh1[1024 + jp];
    cpB2 = bih1[2048 + jp] + bhh1[2048 + jp];
    cpB3 = bih1[3072 + jp] + bhh1[3072 + jp];
    const int dir = jp >> 9, e = jp & 511;
    c0r = enc_c[dir * 8192 + gb * 512 + e];
    c1r = enc_c[(2 + dir) * 8192 + gb * 512 + e];
    st_cv16(xr + gb * 1024 + jp, f2bf(enc_h[dir * 8192 + gb * 512 + e]));
    st_cv16(h1r + gb * 1024 + jp, f2bf(enc_h[(2 + dir) * 8192 + gb * 512 + e]));
  }
  gsyncf(++step, bar);

  // staging coords: thread covers row m = tid>>5, k = kq + j*256
  const int sm = tid >> 5;
  const int skq = (tid & 31) * 8;

  // ---- MAIN LOOP: 129 macro-steps; A = L0[t=s], B = L1[t=s-1] ----
  for (int s = 0; s < 129; ++s) {
    const bool doA = (s < 128), doB = (s >= 1);

    // prefetch ring slabs (plain cached; rings are write-once)
    uint4 rx[4], rh[4] = {}, re[2] = {};
    {
      const u16* sx = xr + (size_t)s * 16384 + sm * 1024;
#pragma unroll
      for (int jj = 0; jj < 4; ++jj) rx[jj] = *(const uint4*)(sx + skq + jj * 256);
      if (doB) {
        const u16* sh = h1r + (size_t)(s - 1) * 16384 + sm * 1024;
#pragma unroll
        for (int jj = 0; jj < 4; ++jj) rh[jj] = *(const uint4*)(sh + skq + jj * 256);
      }
      if (doA) {
        const u16* se = x0b + (size_t)s * 8192 + sm * 512;
#pragma unroll
        for (int jj = 0; jj < 2; ++jj) re[jj] = *(const uint4*)(se + skq + jj * 256);
      }
    }
    // contiguous staging writes ([m][k] slabs)
#pragma unroll
    for (int jj = 0; jj < 4; ++jj) *(uint4*)&xs[sm * 1032 + skq + jj * 256] = rx[jj];
    if (doB) {
#pragma unroll
      for (int jj = 0; jj < 4; ++jj) *(uint4*)&h1s[sm * 1032 + skq + jj * 256] = rh[jj];
    }
    if (doA) {
#pragma unroll
      for (int jj = 0; jj < 2; ++jj) *(uint4*)&xe[sm * 520 + skq + jj * 256] = re[jj];
    }
    __syncthreads();

    // 7 parallel 16-MFMA bursts (weights in registers)
    f32x4 acc = {0.f, 0.f, 0.f, 0.f};
    bool act = false;
    if (wave == 0) { if (doA) { BURST(acc, xe, 520, 0) act = true; } }
    else if (wave == 1) { if (doA) { BURST(acc, xs, 1032, 0) act = true; } }
    else if (wave == 2) { if (doA) { BURST(acc, xs, 1032, 512) act = true; } }
    else if (wave == 3) { if (doB) { BURST(acc, xs, 1032, 0) act = true; } }
    else if (wave == 4) { if (doB) { BURST(acc, xs, 1032, 512) act = true; } }
    else if (wave == 5) { if (doB) { BURST(acc, h1s, 1032, 0) act = true; } }
    else if (wave == 6) { if (doB) { BURST(acc, h1s, 1032, 512) act = true; } }
    if (act) {
#pragma unroll
      for (int r = 0; r < 4; ++r) gls[wave][fr][(lane >> 4) * 4 + r] = acc[r];
    }
    __syncthreads();

    // epilogue: gate math + ring stores (first 64 threads)
    if (tid < 64) {
      const int jp = w4 + gdj;
      if (doA) {
        float gi = gls[0][gdj][gb] + gls[1][gdj][gb] + gls[2][gdj][gb] + cpA0;
        float gf = gls[0][4 + gdj][gb] + gls[1][4 + gdj][gb] + gls[2][4 + gdj][gb] + cpA1;
        float gg = gls[0][8 + gdj][gb] + gls[1][8 + gdj][gb] + gls[2][8 + gdj][gb] + cpA2;
        float go = gls[0][12 + gdj][gb] + gls[1][12 + gdj][gb] + gls[2][12 + gdj][gb] + cpA3;
        c0r = sigf(gf) * c0r + sigf(gi) * tanh_(gg);
        float h = sigf(go) * tanh_(c0r);
        st_cv16(xr + (size_t)(s + 1) * 16384 + gb * 1024 + jp, f2bf(h));
      }
      if (doB) {
        float gi = gls[3][gdj][gb] + gls[4][gdj][gb] + gls[5][gdj][gb] +
                   gls[6][gdj][gb] + cpB0;
        float gf = gls[3][4 + gdj][gb] + gls[4][4 + gdj][gb] + gls[5][4 + gdj][gb] +
                   gls[6][4 + gdj][gb] + cpB1;
        float gg = gls[3][8 + gdj][gb] + gls[4][8 + gdj][gb] + gls[5][8 + gdj][gb] +
                   gls[6][8 + gdj][gb] + cpB2;
        float go = gls[3][12 + gdj][gb] + gls[4][12 + gdj][gb] + gls[5][12 + gdj][gb] +
                   gls[6][12 + gdj][gb] + cpB3;
        c1r = sigf(gf) * c1r + sigf(gi) * tanh_(gg);
        float h = sigf(go) * tanh_(c1r);
        st_cv16(h1r + (size_t)s * 16384 + gb * 1024 + jp, f2bf(h));
        out2b[((s - 1) * 16 + gb) * 1024 + jp] = f2bf(tanh_(h));
      }
    }
    gsyncf(++step, bar);
  }
}

// logits GEMM: A bf16 [2048][1024]; B fp32 [32000][1024] (cvt per tile); C fp32.
__global__ __launch_bounds__(256, 2) void fc_gemm_mfma(
    const u16* __restrict__ A, const float* __restrict__ Bw,
    const float* __restrict__ bias, float* __restrict__ C) {
  __shared__ __align__(16) u16 Al[128][40];
  __shared__ __align__(16) u16 Bl[128][40];

  const int tid = threadIdx.x;
  const int m0 = blockIdx.x * 128;
  const int n0 = blockIdx.y * 128;
  const int wave = tid >> 6;
  const int lane = tid & 63;
  const int wm = (wave & 1) * 64;
  const int wn = (wave >> 1) * 64;
  const int fr = lane & 15;
  const int ks = lane >> 4;

  const int srow = tid >> 1;
  const int sh16 = (tid & 1) * 16;

  const u16* Ag = A + (size_t)(m0 + srow) * 1024 + sh16;
  const float* Bg = Bw + (size_t)(n0 + srow) * 1024 + sh16;

  f32x4 acc[4][4] = {};

  for (int k0 = 0; k0 < 1024; k0 += 32) {
    uint4 a0 = *(const uint4*)(Ag + k0);
    uint4 a1 = *(const uint4*)(Ag + k0 + 8);
    float bfv[16];
    *(float4*)&bfv[0] = *(const float4*)(Bg + k0);
    *(float4*)&bfv[4] = *(const float4*)(Bg + k0 + 4);
    *(float4*)&bfv[8] = *(const float4*)(Bg + k0 + 8);
    *(float4*)&bfv[12] = *(const float4*)(Bg + k0 + 12);
    u16 bu[16];
#pragma unroll
    for (int u = 0; u < 16; ++u) bu[u] = f2bf(bfv[u]);

    __syncthreads();
    *(uint4*)&Al[srow][sh16] = a0;
    *(uint4*)&Al[srow][sh16 + 8] = a1;
    *(uint4*)&Bl[srow][sh16] = *(uint4*)&bu[0];
    *(uint4*)&Bl[srow][sh16 + 8] = *(uint4*)&bu[8];
    __syncthreads();

    bf16x8 af[4], bf[4];
#pragma unroll
    for (int i = 0; i < 4; ++i) af[i] = *(const bf16x8*)&Al[wm + i * 16 + fr][ks * 8];
#pragma unroll
    for (int j = 0; j < 4; ++j) bf[j] = *(const bf16x8*)&Bl[wn + j * 16 + fr][ks * 8];
#pragma unroll
    for (int i = 0; i < 4; ++i)
#pragma unroll
      for (int j = 0; j < 4; ++j)
        acc[i][j] = __builtin_amdgcn_mfma_f32_16x16x32_bf16(af[i], bf[j], acc[i][j], 0, 0, 0);
  }

  float bj[4];
#pragma unroll
  for (int j = 0; j < 4; ++j) bj[j] = bias[n0 + wn + j * 16 + fr];

  const int mrb = (lane >> 4) * 4;
#pragma unroll
  for (int i = 0; i < 4; ++i) {
#pragma unroll
    for (int r = 0; r < 4; ++r) {
      const int m = m0 + wm + i * 16 + mrb + r;
      float* dst = C + ((size_t)(m & 15) * 128 + (m >> 4)) * 32000;
#pragma unroll
      for (int j = 0; j < 4; ++j) {
        dst[n0 + wn + j * 16 + fr] = acc[i][j][r] + bj[j];
      }
    }
  }
}

extern "C" void kernel_launch(void* const* d_in, const int* in_sizes, int n_in,
                              void* d_out, int out_size, void* d_ws, size_t ws_size,
                              hipStream_t stream) {
  const float* enc_h = (const float*)d_in[0];
  const float* enc_c = (const float*)d_in[1];
  const int* tgt = (const int*)d_in[2];
  const float* emb = (const float*)d_in[3];
  const float* wih0 = (const float*)d_in[4];
  const float* whh0 = (const float*)d_in[5];
  const float* bih0 = (const float*)d_in[6];
  const float* bhh0 = (const float*)d_in[7];
  const float* wih1 = (const float*)d_in[8];
  const float* whh1 = (const float*)d_in[9];
  const float* bih1 = (const float*)d_in[10];
  const float* bhh1 = (const float*)d_in[11];
  const float* fcw = (const float*)d_in[12];
  const float* fcb = (const float*)d_in[13];
  float* logits = (float*)d_out;

  unsigned* bar = (unsigned*)d_ws;  // 32 KB barrier region
  hipMemsetAsync(d_ws, 0, 64 + 256 * 64, stream);

  // ws layout (~14.5 MB):
  float* cp = (float*)((char*)d_ws + 32768);  // 4096*16 f32    = 256 KB
  u16* x0b = (u16*)(cp + 65536);              // 2048*512 bf16  = 2 MB
  u16* xr = x0b + 1048576;                    // 129*16384 bf16 = 4.125 MB
  u16* h1r = xr + 2113536;                    // 129*16384 bf16 = 4.125 MB
  u16* out2b = h1r + 2113536;                 // 2048*1024 bf16 = 4 MB

  prep_emb<<<512, 256, 0, stream>>>(tgt, emb, x0b);
  prep_ctx<<<256, 256, 0, stream>>>(enc_h, wih0, cp);
  dec_seq_rw<<<NBLK, 512, 0, stream>>>(enc_h, enc_c, wih0, whh0, wih1, whh1,
                                       bih0, bhh0, bih1, bhh1, cp, x0b,
                                       xr, h1r, out2b, bar);
  fc_gemm_mfma<<<dim3(16, 250), 256, 0, stream>>>(out2b, fcw, fcb, logits);
}

// Round 12
// 1048.166 us; speedup vs baseline: 1.1955x; 1.0312x over previous
//
#include <hip/hip_runtime.h>

// Decoder: B=16, T=128, V=32000, E=512, H=1024 (2 LSTM layers), CTX=2048.
// R12: barrier-latency package on R11's register-weight skeleton.
//   - 128 blocks x 8 units (2 bursts/wave, weights in VGPRs): half producers,
//     half flags, 1/4 poll traffic, stragglers max over 128 not 256.
//   - Flags at 128B stride (one per line; R11's 64B stride shared lines).
//   - emb slab (static) prefetched + LDS-staged BEFORE the barrier; only the
//     two fresh slabs (x, h1) staged on the post-barrier critical path.
//   - All-wave vmcnt(0) drain at barrier entry (epilogue spans waves 0-1).
// fc_gemm_mfma: bf16 MFMA GEMM -> [16][128][32000] logits (~125us).

#define NBLK 128

typedef float f32x4 __attribute__((ext_vector_type(4)));
typedef __bf16 bf16x8 __attribute__((ext_vector_type(8)));
typedef unsigned short u16;

__device__ __forceinline__ float sigf(float x) { return 1.0f / (1.0f + __expf(-x)); }
__device__ __forceinline__ float tanh_(float x) {
  x = fminf(15.0f, fmaxf(-15.0f, x));
  float e = __expf(2.0f * x);
  return (e - 1.0f) / (e + 1.0f);
}

__device__ __forceinline__ u16 f2bf(float f) {
  __bf16 h = (__bf16)f;  // RNE
  return __builtin_bit_cast(u16, h);
}

__device__ __forceinline__ bf16x8 cvt8(float4 a, float4 b) {
  bf16x8 v;
  v[0] = (__bf16)a.x; v[1] = (__bf16)a.y; v[2] = (__bf16)a.z; v[3] = (__bf16)a.w;
  v[4] = (__bf16)b.x; v[5] = (__bf16)b.y; v[6] = (__bf16)b.z; v[7] = (__bf16)b.w;
  return v;
}

// Coherent (write-through) bf16 store.
__device__ __forceinline__ void st_cv16(u16* p, u16 v) {
  unsigned vv = v;
  asm volatile("global_store_short %0, %1, off sc0 sc1" :: "v"(p), "v"(vv) : "memory");
}

// Plain sc0/sc1 flag store (caller guarantees data already drained).
__device__ __forceinline__ void flag_store(unsigned* p, unsigned v) {
  asm volatile("global_store_dword %0, %1, off sc0 sc1" :: "v"(p), "v"(v) : "memory");
}

// 2 bypass flag loads in flight (no atomic lowering -> no buffer_inv).
__device__ __forceinline__ void ld2_flags(const unsigned* p0, const unsigned* p1,
                                          unsigned& a, unsigned& b) {
  asm volatile(
      "global_load_dword %0, %2, off sc0 sc1\n\t"
      "global_load_dword %1, %3, off sc0 sc1\n\t"
      "s_waitcnt vmcnt(0)"
      : "=&v"(a), "=&v"(b)
      : "v"(p0), "v"(p1)
      : "memory");
}

// Flat one-hop barrier: ALL threads drain their wave's stores first (epilogue
// spans waves 0-1), then block flag (own 128B line), wave0 polls 2 flags/lane.
__device__ __forceinline__ void gsyncf(unsigned step, unsigned* bar) {
  asm volatile("s_waitcnt vmcnt(0)" ::: "memory");
  __syncthreads();
  const int tid = threadIdx.x;
  if (tid == 0) flag_store(bar + 32 + blockIdx.x * 32, step);
  if (tid < 64) {
    const unsigned* p0 = bar + 32 + tid * 64;   // block 2*tid
    const unsigned* p1 = p0 + 32;               // block 2*tid+1
    for (;;) {
      unsigned a, b;
      ld2_flags(p0, p1, a, b);
      if (__all((a >= step) & (b >= step))) break;
      __builtin_amdgcn_s_sleep(1);
    }
    asm volatile("" ::: "memory");
  }
  __syncthreads();
}

__device__ __forceinline__ void dot4(float& a, float4 wv, float4 xv) {
  a = fmaf(wv.x, xv.x, a);
  a = fmaf(wv.y, xv.y, a);
  a = fmaf(wv.z, xv.z, a);
  a = fmaf(wv.w, xv.w, a);
}

// ---- prep: gather token embeddings as bf16: x0b[tb][512], tb = t*16+b ----
__global__ void prep_emb(const int* __restrict__ tgt, const float* __restrict__ emb,
                         u16* __restrict__ x0b) {
  const int g = blockIdx.x * blockDim.x + threadIdx.x;  // 131072 total
  const int col8 = (g & 63) * 8;
  const int tb = g >> 6;            // 0..2047
  const int t = tb >> 4, b = tb & 15;
  const int tok = (t == 0) ? 1 : tgt[b * 128 + (t - 1)];
  const float* s = emb + (size_t)tok * 512 + col8;
  float4 a = *(const float4*)s;
  float4 bb = *(const float4*)(s + 4);
  __align__(16) u16 r[8] = {f2bf(a.x), f2bf(a.y), f2bf(a.z), f2bf(a.w),
                            f2bf(bb.x), f2bf(bb.y), f2bf(bb.z), f2bf(bb.w)};
  *(uint4*)(x0b + (size_t)tb * 512 + col8) = *(uint4*)r;
}

// ---- prep: fp32 ctx projection cp[j][b] = sum_k wih0[j][512+k]*ctx[b][k] ----
__global__ __launch_bounds__(256, 1) void prep_ctx(const float* __restrict__ enc_h,
                                                   const float* __restrict__ wih0,
                                                   float* __restrict__ cp) {
  __shared__ float ctx[16][2052];
  const int tid = threadIdx.x;
#pragma unroll
  for (int c = 0; c < 32; ++c) {
    int f4 = tid + c * 256;
    int b = f4 >> 9, kq = f4 & 511;
    *(float4*)&ctx[b][kq * 4] =
        *(const float4*)(enc_h + (kq >> 7) * 8192 + b * 512 + (kq & 127) * 4);
  }
  __syncthreads();
  const int jr = tid >> 4, b = tid & 15;
  const int j = blockIdx.x * 16 + jr;
  const float* w = wih0 + (size_t)j * 2560 + 512;
  float a0 = 0.f, a1 = 0.f, a2 = 0.f, a3 = 0.f;
  for (int k = 0; k < 2048; k += 16) {
    float4 w0 = *(const float4*)(w + k);
    float4 w1 = *(const float4*)(w + k + 4);
    float4 w2 = *(const float4*)(w + k + 8);
    float4 w3 = *(const float4*)(w + k + 12);
    float4 x0 = *(const float4*)&ctx[b][k];
    float4 x1 = *(const float4*)&ctx[b][k + 4];
    float4 x2 = *(const float4*)&ctx[b][k + 8];
    float4 x3 = *(const float4*)&ctx[b][k + 12];
    dot4(a0, w0, x0); dot4(a1, w1, x1); dot4(a2, w2, x2); dot4(a3, w3, x3);
  }
  cp[(size_t)j * 16 + b] = a0 + a1 + a2 + a3;
}

// 16 chained MFMAs; A-frags from LDS slab BP (stride S u16, col off XOFF),
// B-frags from register weights BW[16].
#define BURST(ACC, BP, S, XOFF, BW)                                            \
  _Pragma("unroll")                                                            \
  for (int mm = 0; mm < 16; ++mm) {                                            \
    bf16x8 av = *(const bf16x8*)&(BP)[fr * (S) + (XOFF) + mm * 32 + ks8];      \
    ACC = __builtin_amdgcn_mfma_f32_16x16x32_bf16(av, (BW)[mm], ACC, 0, 0, 0); \
  }

// Load one burst's 16 weight fragments into registers.
// q = c*2 + tile; c: 0 emb(wih0) | 1,2 hh0 k0/k1 | 3,4 ih1 k0/k1 | 5,6 hh1.
// N-tile rows: gate = tile*2 + (nn>>3), unit = nn&7 (nn = lane&15).
__device__ __forceinline__ void loadw(bf16x8* dst, int q, int w8, int lane,
                                      const float* wih0, const float* whh0,
                                      const float* wih1, const float* whh1) {
  const int c = q >> 1, tile = q & 1;
  const int nn = lane & 15;
  const int gate = tile * 2 + (nn >> 3);
  const int unit = nn & 7;
  const int j = gate * 1024 + w8 + unit;
  const float* src;
  size_t stride = 1024;
  int ko = 0;
  if (c == 0) { src = wih0; stride = 2560; ko = 0; }
  else if (c <= 2) { src = whh0; ko = (c - 1) * 512; }
  else if (c <= 4) { src = wih1; ko = (c - 3) * 512; }
  else { src = whh1; ko = (c - 5) * 512; }
  const float* base = src + (size_t)j * stride + ko + ((lane >> 4) * 8);
#pragma unroll
  for (int mm = 0; mm < 16; ++mm) {
    const float* sp = base + mm * 32;
    dst[mm] = cvt8(*(const float4*)sp, *(const float4*)(sp + 4));
  }
}

// ---------------- persistent MFMA decoder (128 blocks x 8 units) ----------
// Rings (bf16, write-once): xr slot t+1 = h0/x1[t] (slot 0 = init h0);
//                           h1r slot t+1 = h1[t] (slot 0 = init h1).
__global__ __launch_bounds__(512, 2) void dec_seq_rw2(
    const float* __restrict__ enc_h, const float* __restrict__ enc_c,
    const float* __restrict__ wih0, const float* __restrict__ whh0,
    const float* __restrict__ wih1, const float* __restrict__ whh1,
    const float* __restrict__ bih0, const float* __restrict__ bhh0,
    const float* __restrict__ bih1, const float* __restrict__ bhh1,
    const float* __restrict__ cp, const u16* __restrict__ x0b,
    u16* __restrict__ xr, u16* __restrict__ h1r,
    u16* __restrict__ out2b, unsigned* bar) {
  __shared__ u16 xe[16 * 520];       // emb slab (pre-barrier staged)
  __shared__ u16 xs[16 * 1032];      // x slot s
  __shared__ u16 h1s[16 * 1032];     // h1 slot s-1
  __shared__ float gls[14][16][17];  // partial acc tiles [q][n][batch]

  const int tid = threadIdx.x;
  const int wgid = blockIdx.x;
  const int w8 = wgid * 8;
  const int lane = tid & 63;
  const int wave = tid >> 6;
  const int fr = lane & 15;
  const int ks8 = (lane >> 4) * 8;
  unsigned step = 0;

  // ---- INIT: this wave's weight fragments -> registers ----
  // wave w<6: bursts q=2w (tile0) and 2w+1 (tile1), shared source c=w.
  // wave6: q=12 (c6 tile0); wave7: q=13 (c6 tile1) in its bw0.
  bf16x8 bw0[16], bw1[16];
  const int q0 = (wave < 6) ? 2 * wave : (wave == 6 ? 12 : 13);
  loadw(bw0, q0, w8, lane, wih0, whh0, wih1, whh1);
  if (wave < 6) loadw(bw1, 2 * wave + 1, w8, lane, wih0, whh0, wih1, whh1);
  else {
#pragma unroll
    for (int mm = 0; mm < 16; ++mm) bw1[mm] = bf16x8{};
  }

  // ---- INIT per-thread gate state (tid<128: unit gdj 0..7, batch gb) ----
  const int gdj = (tid >> 4) & 7;
  const int gb = tid & 15;
  float cpA0 = 0.f, cpA1 = 0.f, cpA2 = 0.f, cpA3 = 0.f;
  float cpB0 = 0.f, cpB1 = 0.f, cpB2 = 0.f, cpB3 = 0.f;
  float c0r = 0.f, c1r = 0.f;
  if (tid < 128) {
    const int jp = w8 + gdj;
    cpA0 = cp[(size_t)(jp) * 16 + gb] + bih0[jp] + bhh0[jp];
    cpA1 = cp[(size_t)(1024 + jp) * 16 + gb] + bih0[1024 + jp] + bhh0[1024 + jp];
    cpA2 = cp[(size_t)(2048 + jp) * 16 + gb] + bih0[2048 + jp] + bhh0[2048 + jp];
    cpA3 = cp[(size_t)(3072 + jp) * 16 + gb] + bih0[3072 + jp] + bhh0[3072 + jp];
    cpB0 = bih1[jp] + bhh1[jp];
    cpB1 = bih1[1024 + jp] + bhh1[1024 + jp];
    cpB2 = bih1[2048 + jp] + bhh1[2048 + jp];
    cpB3 = bih1[3072 + jp] + bhh1[3072 + jp];
    const int dir = jp >> 9, e = jp & 511;
    c0r = enc_c[dir * 8192 + gb * 512 + e];
    c1r = enc_c[(2 + dir) * 8192 + gb * 512 + e];
    st_cv16(xr + gb * 1024 + jp, f2bf(enc_h[dir * 8192 + gb * 512 + e]));
    st_cv16(h1r + gb * 1024 + jp, f2bf(enc_h[(2 + dir) * 8192 + gb * 512 + e]));
  }

  // staging coords: thread covers row m = tid>>5, k = kq + j*256
  const int sm = tid >> 5;
  const int skq = (tid & 31) * 8;

  // pre-stage emb slab for s=0 (static data; before first barrier)
  {
    const u16* se = x0b + sm * 512;
#pragma unroll
    for (int jj = 0; jj < 2; ++jj)
      *(uint4*)&xe[sm * 520 + skq + jj * 256] = *(const uint4*)(se + skq + jj * 256);
  }
  gsyncf(++step, bar);

  // ---- MAIN LOOP: 129 macro-steps; A = L0[t=s], B = L1[t=s-1] ----
  for (int s = 0; s < 129; ++s) {
    const bool doA = (s < 128), doB = (s >= 1);

    // prefetch fresh ring slabs (barrier-dependent) + next emb slab (static)
    uint4 rx[4], rh[4] = {}, re[2] = {};
    {
      const u16* sx = xr + (size_t)s * 16384 + sm * 1024;
#pragma unroll
      for (int jj = 0; jj < 4; ++jj) rx[jj] = *(const uint4*)(sx + skq + jj * 256);
      if (doB) {
        const u16* sh = h1r + (size_t)(s - 1) * 16384 + sm * 1024;
#pragma unroll
        for (int jj = 0; jj < 4; ++jj) rh[jj] = *(const uint4*)(sh + skq + jj * 256);
      }
      if (s < 127) {  // emb slab for step s+1
        const u16* se = x0b + (size_t)(s + 1) * 8192 + sm * 512;
#pragma unroll
        for (int jj = 0; jj < 2; ++jj) re[jj] = *(const uint4*)(se + skq + jj * 256);
      }
    }
    // stage fresh slabs ([m][k], contiguous writes)
#pragma unroll
    for (int jj = 0; jj < 4; ++jj) *(uint4*)&xs[sm * 1032 + skq + jj * 256] = rx[jj];
    if (doB) {
#pragma unroll
      for (int jj = 0; jj < 4; ++jj) *(uint4*)&h1s[sm * 1032 + skq + jj * 256] = rh[jj];
    }
    __syncthreads();

    // 14 bursts over 8 waves (waves 0-5: 2 bursts; waves 6-7: 1)
    f32x4 acc0 = {0.f, 0.f, 0.f, 0.f}, acc1 = {0.f, 0.f, 0.f, 0.f};
    bool act0 = false, act1 = false;
    if (wave == 0) { if (doA) { BURST(acc0, xe, 520, 0, bw0) BURST(acc1, xe, 520, 0, bw1) act0 = act1 = true; } }
    else if (wave == 1) { if (doA) { BURST(acc0, xs, 1032, 0, bw0) BURST(acc1, xs, 1032, 0, bw1) act0 = act1 = true; } }
    else if (wave == 2) { if (doA) { BURST(acc0, xs, 1032, 512, bw0) BURST(acc1, xs, 1032, 512, bw1) act0 = act1 = true; } }
    else if (wave == 3) { if (doB) { BURST(acc0, xs, 1032, 0, bw0) BURST(acc1, xs, 1032, 0, bw1) act0 = act1 = true; } }
    else if (wave == 4) { if (doB) { BURST(acc0, xs, 1032, 512, bw0) BURST(acc1, xs, 1032, 512, bw1) act0 = act1 = true; } }
    else if (wave == 5) { if (doB) { BURST(acc0, h1s, 1032, 0, bw0) BURST(acc1, h1s, 1032, 0, bw1) act0 = act1 = true; } }
    else if (wave == 6) { if (doB) { BURST(acc0, h1s, 1032, 512, bw0) act0 = true; } }
    else { if (doB) { BURST(acc0, h1s, 1032, 512, bw0) act0 = true; } }
    if (act0) {
#pragma unroll
      for (int r = 0; r < 4; ++r) gls[q0][fr][(lane >> 4) * 4 + r] = acc0[r];
    }
    if (act1) {
#pragma unroll
      for (int r = 0; r < 4; ++r) gls[q0 + 1][fr][(lane >> 4) * 4 + r] = acc1[r];
    }
    __syncthreads();

    // stage next emb slab (xe consumed; safe after sync; read after barrier)
    if (s < 127) {
#pragma unroll
      for (int jj = 0; jj < 2; ++jj) *(uint4*)&xe[sm * 520 + skq + jj * 256] = re[jj];
    }

    // epilogue: gate math + ring stores (waves 0-1)
    if (tid < 128) {
      const int jp = w8 + gdj;
      if (doA) {
        // A sources: q {0,2,4} tile0 (gates i,f), {1,3,5} tile1 (gates g,o)
        float gi = gls[0][gdj][gb] + gls[2][gdj][gb] + gls[4][gdj][gb] + cpA0;
        float gf = gls[0][8 + gdj][gb] + gls[2][8 + gdj][gb] + gls[4][8 + gdj][gb] + cpA1;
        float gg = gls[1][gdj][gb] + gls[3][gdj][gb] + gls[5][gdj][gb] + cpA2;
        float go = gls[1][8 + gdj][gb] + gls[3][8 + gdj][gb] + gls[5][8 + gdj][gb] + cpA3;
        c0r = sigf(gf) * c0r + sigf(gi) * tanh_(gg);
        float h = sigf(go) * tanh_(c0r);
        st_cv16(xr + (size_t)(s + 1) * 16384 + gb * 1024 + jp, f2bf(h));
      }
      if (doB) {
        // B sources: q {6,8,10,12} tile0, {7,9,11,13} tile1
        float gi = gls[6][gdj][gb] + gls[8][gdj][gb] + gls[10][gdj][gb] +
                   gls[12][gdj][gb] + cpB0;
        float gf = gls[6][8 + gdj][gb] + gls[8][8 + gdj][gb] + gls[10][8 + gdj][gb] +
                   gls[12][8 + gdj][gb] + cpB1;
        float gg = gls[7][gdj][gb] + gls[9][gdj][gb] + gls[11][gdj][gb] +
                   gls[13][gdj][gb] + cpB2;
        float go = gls[7][8 + gdj][gb] + gls[9][8 + gdj][gb] + gls[11][8 + gdj][gb] +
                   gls[13][8 + gdj][gb] + cpB3;
        c1r = sigf(gf) * c1r + sigf(gi) * tanh_(gg);
        float h = sigf(go) * tanh_(c1r);
        st_cv16(h1r + (size_t)s * 16384 + gb * 1024 + jp, f2bf(h));
        out2b[((s - 1) * 16 + gb) * 1024 + jp] = f2bf(tanh_(h));
      }
    }
    gsyncf(++step, bar);
  }
}

// logits GEMM: A bf16 [2048][1024]; B fp32 [32000][1024] (cvt per tile); C fp32.
__global__ __launch_bounds__(256, 2) void fc_gemm_mfma(
    const u16* __restrict__ A, const float* __restrict__ Bw,
    const float* __restrict__ bias, float* __restrict__ C) {
  __shared__ __align__(16) u16 Al[128][40];
  __shared__ __align__(16) u16 Bl[128][40];

  const int tid = threadIdx.x;
  const int m0 = blockIdx.x * 128;
  const int n0 = blockIdx.y * 128;
  const int wave = tid >> 6;
  const int lane = tid & 63;
  const int wm = (wave & 1) * 64;
  const int wn = (wave >> 1) * 64;
  const int fr = lane & 15;
  const int ks = lane >> 4;

  const int srow = tid >> 1;
  const int sh16 = (tid & 1) * 16;

  const u16* Ag = A + (size_t)(m0 + srow) * 1024 + sh16;
  const float* Bg = Bw + (size_t)(n0 + srow) * 1024 + sh16;

  f32x4 acc[4][4] = {};

  for (int k0 = 0; k0 < 1024; k0 += 32) {
    uint4 a0 = *(const uint4*)(Ag + k0);
    uint4 a1 = *(const uint4*)(Ag + k0 + 8);
    float bfv[16];
    *(float4*)&bfv[0] = *(const float4*)(Bg + k0);
    *(float4*)&bfv[4] = *(const float4*)(Bg + k0 + 4);
    *(float4*)&bfv[8] = *(const float4*)(Bg + k0 + 8);
    *(float4*)&bfv[12] = *(const float4*)(Bg + k0 + 12);
    u16 bu[16];
#pragma unroll
    for (int u = 0; u < 16; ++u) bu[u] = f2bf(bfv[u]);

    __syncthreads();
    *(uint4*)&Al[srow][sh16] = a0;
    *(uint4*)&Al[srow][sh16 + 8] = a1;
    *(uint4*)&Bl[srow][sh16] = *(uint4*)&bu[0];
    *(uint4*)&Bl[srow][sh16 + 8] = *(uint4*)&bu[8];
    __syncthreads();

    bf16x8 af[4], bf[4];
#pragma unroll
    for (int i = 0; i < 4; ++i) af[i] = *(const bf16x8*)&Al[wm + i * 16 + fr][ks * 8];
#pragma unroll
    for (int j = 0; j < 4; ++j) bf[j] = *(const bf16x8*)&Bl[wn + j * 16 + fr][ks * 8];
#pragma unroll
    for (int i = 0; i < 4; ++i)
#pragma unroll
      for (int j = 0; j < 4; ++j)
        acc[i][j] = __builtin_amdgcn_mfma_f32_16x16x32_bf16(af[i], bf[j], acc[i][j], 0, 0, 0);
  }

  float bj[4];
#pragma unroll
  for (int j = 0; j < 4; ++j) bj[j] = bias[n0 + wn + j * 16 + fr];

  const int mrb = (lane >> 4) * 4;
#pragma unroll
  for (int i = 0; i < 4; ++i) {
#pragma unroll
    for (int r = 0; r < 4; ++r) {
      const int m = m0 + wm + i * 16 + mrb + r;
      float* dst = C + ((size_t)(m & 15) * 128 + (m >> 4)) * 32000;
#pragma unroll
      for (int j = 0; j < 4; ++j) {
        dst[n0 + wn + j * 16 + fr] = acc[i][j][r] + bj[j];
      }
    }
  }
}

extern "C" void kernel_launch(void* const* d_in, const int* in_sizes, int n_in,
                              void* d_out, int out_size, void* d_ws, size_t ws_size,
                              hipStream_t stream) {
  const float* enc_h = (const float*)d_in[0];
  const float* enc_c = (const float*)d_in[1];
  const int* tgt = (const int*)d_in[2];
  const float* emb = (const float*)d_in[3];
  const float* wih0 = (const float*)d_in[4];
  const float* whh0 = (const float*)d_in[5];
  const float* bih0 = (const float*)d_in[6];
  const float* bhh0 = (const float*)d_in[7];
  const float* wih1 = (const float*)d_in[8];
  const float* whh1 = (const float*)d_in[9];
  const float* bih1 = (const float*)d_in[10];
  const float* bhh1 = (const float*)d_in[11];
  const float* fcw = (const float*)d_in[12];
  const float* fcb = (const float*)d_in[13];
  float* logits = (float*)d_out;

  unsigned* bar = (unsigned*)d_ws;  // 32 KB barrier region (flags @128B stride)
  hipMemsetAsync(d_ws, 0, 32768, stream);

  // ws layout (~14.5 MB):
  float* cp = (float*)((char*)d_ws + 32768);  // 4096*16 f32    = 256 KB
  u16* x0b = (u16*)(cp + 65536);              // 2048*512 bf16  = 2 MB
  u16* xr = x0b + 1048576;                    // 129*16384 bf16 = 4.125 MB
  u16* h1r = xr + 2113536;                    // 129*16384 bf16 = 4.125 MB
  u16* out2b = h1r + 2113536;                 // 2048*1024 bf16 = 4 MB

  prep_emb<<<512, 256, 0, stream>>>(tgt, emb, x0b);
  prep_ctx<<<256, 256, 0, stream>>>(enc_h, wih0, cp);
  dec_seq_rw2<<<NBLK, 512, 0, stream>>>(enc_h, enc_c, wih0, whh0, wih1, whh1,
                                        bih0, bhh0, bih1, bhh1, cp, x0b,
                                        xr, h1r, out2b, bar);
  fc_gemm_mfma<<<dim3(16, 250), 256, 0, stream>>>(out2b, fcw, fcb, logits);
}

// Round 13
// 990.481 us; speedup vs baseline: 1.2652x; 1.0582x over previous
//
#include <hip/hip_runtime.h>

// Decoder: B=16, T=128, V=32000, E=512, H=1024 (2 LSTM layers), CTX=2048.
// R13: dec_seq_rw2 unchanged (720us, barrier-latency floor for the all-to-all
//   recurrence). Auxiliary-time package:
//   - fcw pre-converted to bf16 once (prep_bf16) + bf16-B fc_gemm_bf
//     (halves B traffic, no per-tile convert). ws-gated w/ fp32 fallback.
//   - prep_ctx2: coalesced split-K (16 lanes/row, 256B contiguous w-reads,
//     shfl_xor group reduce) replaces the latency-bound per-thread-row scan.

#define NBLK 128

typedef float f32x4 __attribute__((ext_vector_type(4)));
typedef __bf16 bf16x8 __attribute__((ext_vector_type(8)));
typedef unsigned short u16;

__device__ __forceinline__ float sigf(float x) { return 1.0f / (1.0f + __expf(-x)); }
__device__ __forceinline__ float tanh_(float x) {
  x = fminf(15.0f, fmaxf(-15.0f, x));
  float e = __expf(2.0f * x);
  return (e - 1.0f) / (e + 1.0f);
}

__device__ __forceinline__ u16 f2bf(float f) {
  __bf16 h = (__bf16)f;  // RNE
  return __builtin_bit_cast(u16, h);
}

__device__ __forceinline__ bf16x8 cvt8(float4 a, float4 b) {
  bf16x8 v;
  v[0] = (__bf16)a.x; v[1] = (__bf16)a.y; v[2] = (__bf16)a.z; v[3] = (__bf16)a.w;
  v[4] = (__bf16)b.x; v[5] = (__bf16)b.y; v[6] = (__bf16)b.z; v[7] = (__bf16)b.w;
  return v;
}

// Coherent (write-through) bf16 store.
__device__ __forceinline__ void st_cv16(u16* p, u16 v) {
  unsigned vv = v;
  asm volatile("global_store_short %0, %1, off sc0 sc1" :: "v"(p), "v"(vv) : "memory");
}

// Plain sc0/sc1 flag store (caller guarantees data already drained).
__device__ __forceinline__ void flag_store(unsigned* p, unsigned v) {
  asm volatile("global_store_dword %0, %1, off sc0 sc1" :: "v"(p), "v"(v) : "memory");
}

// 2 bypass flag loads in flight (no atomic lowering -> no buffer_inv).
__device__ __forceinline__ void ld2_flags(const unsigned* p0, const unsigned* p1,
                                          unsigned& a, unsigned& b) {
  asm volatile(
      "global_load_dword %0, %2, off sc0 sc1\n\t"
      "global_load_dword %1, %3, off sc0 sc1\n\t"
      "s_waitcnt vmcnt(0)"
      : "=&v"(a), "=&v"(b)
      : "v"(p0), "v"(p1)
      : "memory");
}

// Flat one-hop barrier: all threads drain stores, block flag (own 128B line),
// wave0 polls 2 flags/lane.
__device__ __forceinline__ void gsyncf(unsigned step, unsigned* bar) {
  asm volatile("s_waitcnt vmcnt(0)" ::: "memory");
  __syncthreads();
  const int tid = threadIdx.x;
  if (tid == 0) flag_store(bar + 32 + blockIdx.x * 32, step);
  if (tid < 64) {
    const unsigned* p0 = bar + 32 + tid * 64;   // block 2*tid
    const unsigned* p1 = p0 + 32;               // block 2*tid+1
    for (;;) {
      unsigned a, b;
      ld2_flags(p0, p1, a, b);
      if (__all((a >= step) & (b >= step))) break;
      __builtin_amdgcn_s_sleep(1);
    }
    asm volatile("" ::: "memory");
  }
  __syncthreads();
}

__device__ __forceinline__ void dot4(float& a, float4 wv, float4 xv) {
  a = fmaf(wv.x, xv.x, a);
  a = fmaf(wv.y, xv.y, a);
  a = fmaf(wv.z, xv.z, a);
  a = fmaf(wv.w, xv.w, a);
}

// ---- prep: fp32 -> bf16 contiguous convert (weights, fcw) ----
__global__ void prep_bf16(const float* __restrict__ src, u16* __restrict__ dst, int n8) {
  for (int i = blockIdx.x * blockDim.x + threadIdx.x; i < n8; i += gridDim.x * blockDim.x) {
    float4 a = *(const float4*)(src + (size_t)i * 8);
    float4 b = *(const float4*)(src + (size_t)i * 8 + 4);
    bf16x8 v = cvt8(a, b);
    *(uint4*)(dst + (size_t)i * 8) = __builtin_bit_cast(uint4, v);
  }
}

// ---- prep: gather token embeddings as bf16: x0b[tb][512], tb = t*16+b ----
__global__ void prep_emb(const int* __restrict__ tgt, const float* __restrict__ emb,
                         u16* __restrict__ x0b) {
  const int g = blockIdx.x * blockDim.x + threadIdx.x;  // 131072 total
  const int col8 = (g & 63) * 8;
  const int tb = g >> 6;            // 0..2047
  const int t = tb >> 4, b = tb & 15;
  const int tok = (t == 0) ? 1 : tgt[b * 128 + (t - 1)];
  const float* s = emb + (size_t)tok * 512 + col8;
  float4 a = *(const float4*)s;
  float4 bb = *(const float4*)(s + 4);
  bf16x8 v = cvt8(a, bb);
  *(uint4*)(x0b + (size_t)tb * 512 + col8) = __builtin_bit_cast(uint4, v);
}

// ---- prep: cp[j][b] = sum_k wih0[j][512+k]*ctx[b][k]  (coalesced split-K) --
// 256 blocks x 256 threads; thread = (row r = tid>>4, lane l = tid&15).
// Lane l covers k = l*4 + 64*i -> 16 lanes read 256B contiguous per group.
// 16 batch-accumulators per thread; shfl_xor reduce over the 16-lane group.
__global__ __launch_bounds__(256, 1) void prep_ctx2(const float* __restrict__ enc_h,
                                                    const float* __restrict__ wih0,
                                                    float* __restrict__ cp) {
  __shared__ float ctx[16][2052];
  const int tid = threadIdx.x;
#pragma unroll
  for (int c = 0; c < 32; ++c) {
    int f4 = tid + c * 256;
    int b = f4 >> 9, kq = f4 & 511;
    *(float4*)&ctx[b][kq * 4] =
        *(const float4*)(enc_h + (kq >> 7) * 8192 + b * 512 + (kq & 127) * 4);
  }
  __syncthreads();
  const int r = tid >> 4, l = tid & 15;
  const int j = blockIdx.x * 16 + r;
  const float* w = wih0 + (size_t)j * 2560 + 512;
  float acc[16] = {};
#pragma unroll 4
  for (int i = 0; i < 32; ++i) {
    const int k = l * 4 + i * 64;
    const float4 w4 = *(const float4*)(w + k);
#pragma unroll
    for (int b = 0; b < 16; ++b) dot4(acc[b], w4, *(const float4*)&ctx[b][k]);
  }
#pragma unroll
  for (int off = 1; off < 16; off <<= 1)
#pragma unroll
    for (int b = 0; b < 16; ++b) acc[b] += __shfl_xor(acc[b], off);
  cp[(size_t)j * 16 + l] = acc[l];
}

// 16 chained MFMAs; A-frags from LDS slab BP (stride S u16, col off XOFF),
// B-frags from register weights BW[16].
#define BURST(ACC, BP, S, XOFF, BW)                                            \
  _Pragma("unroll")                                                            \
  for (int mm = 0; mm < 16; ++mm) {                                            \
    bf16x8 av = *(const bf16x8*)&(BP)[fr * (S) + (XOFF) + mm * 32 + ks8];      \
    ACC = __builtin_amdgcn_mfma_f32_16x16x32_bf16(av, (BW)[mm], ACC, 0, 0, 0); \
  }

// Load one burst's 16 weight fragments into registers.
// q = c*2 + tile; c: 0 emb(wih0) | 1,2 hh0 k0/k1 | 3,4 ih1 k0/k1 | 5,6 hh1.
__device__ __forceinline__ void loadw(bf16x8* dst, int q, int w8, int lane,
                                      const float* wih0, const float* whh0,
                                      const float* wih1, const float* whh1) {
  const int c = q >> 1, tile = q & 1;
  const int nn = lane & 15;
  const int gate = tile * 2 + (nn >> 3);
  const int unit = nn & 7;
  const int j = gate * 1024 + w8 + unit;
  const float* src;
  size_t stride = 1024;
  int ko = 0;
  if (c == 0) { src = wih0; stride = 2560; ko = 0; }
  else if (c <= 2) { src = whh0; ko = (c - 1) * 512; }
  else if (c <= 4) { src = wih1; ko = (c - 3) * 512; }
  else { src = whh1; ko = (c - 5) * 512; }
  const float* base = src + (size_t)j * stride + ko + ((lane >> 4) * 8);
#pragma unroll
  for (int mm = 0; mm < 16; ++mm) {
    const float* sp = base + mm * 32;
    dst[mm] = cvt8(*(const float4*)sp, *(const float4*)(sp + 4));
  }
}

// ---------------- persistent MFMA decoder (128 blocks x 8 units) ----------
__global__ __launch_bounds__(512, 2) void dec_seq_rw2(
    const float* __restrict__ enc_h, const float* __restrict__ enc_c,
    const float* __restrict__ wih0, const float* __restrict__ whh0,
    const float* __restrict__ wih1, const float* __restrict__ whh1,
    const float* __restrict__ bih0, const float* __restrict__ bhh0,
    const float* __restrict__ bih1, const float* __restrict__ bhh1,
    const float* __restrict__ cp, const u16* __restrict__ x0b,
    u16* __restrict__ xr, u16* __restrict__ h1r,
    u16* __restrict__ out2b, unsigned* bar) {
  __shared__ u16 xe[16 * 520];       // emb slab (pre-barrier staged)
  __shared__ u16 xs[16 * 1032];      // x slot s
  __shared__ u16 h1s[16 * 1032];     // h1 slot s-1
  __shared__ float gls[14][16][17];  // partial acc tiles [q][n][batch]

  const int tid = threadIdx.x;
  const int wgid = blockIdx.x;
  const int w8 = wgid * 8;
  const int lane = tid & 63;
  const int wave = tid >> 6;
  const int fr = lane & 15;
  const int ks8 = (lane >> 4) * 8;
  unsigned step = 0;

  bf16x8 bw0[16], bw1[16];
  const int q0 = (wave < 6) ? 2 * wave : (wave == 6 ? 12 : 13);
  loadw(bw0, q0, w8, lane, wih0, whh0, wih1, whh1);
  if (wave < 6) loadw(bw1, 2 * wave + 1, w8, lane, wih0, whh0, wih1, whh1);
  else {
#pragma unroll
    for (int mm = 0; mm < 16; ++mm) bw1[mm] = bf16x8{};
  }

  const int gdj = (tid >> 4) & 7;
  const int gb = tid & 15;
  float cpA0 = 0.f, cpA1 = 0.f, cpA2 = 0.f, cpA3 = 0.f;
  float cpB0 = 0.f, cpB1 = 0.f, cpB2 = 0.f, cpB3 = 0.f;
  float c0r = 0.f, c1r = 0.f;
  if (tid < 128) {
    const int jp = w8 + gdj;
    cpA0 = cp[(size_t)(jp) * 16 + gb] + bih0[jp] + bhh0[jp];
    cpA1 = cp[(size_t)(1024 + jp) * 16 + gb] + bih0[1024 + jp] + bhh0[1024 + jp];
    cpA2 = cp[(size_t)(2048 + jp) * 16 + gb] + bih0[2048 + jp] + bhh0[2048 + jp];
    cpA3 = cp[(size_t)(3072 + jp) * 16 + gb] + bih0[3072 + jp] + bhh0[3072 + jp];
    cpB0 = bih1[jp] + bhh1[jp];
    cpB1 = bih1[1024 + jp] + bhh1[1024 + jp];
    cpB2 = bih1[2048 + jp] + bhh1[2048 + jp];
    cpB3 = bih1[3072 + jp] + bhh1[3072 + jp];
    const int dir = jp >> 9, e = jp & 511;
    c0r = enc_c[dir * 8192 + gb * 512 + e];
    c1r = enc_c[(2 + dir) * 8192 + gb * 512 + e];
    st_cv16(xr + gb * 1024 + jp, f2bf(enc_h[dir * 8192 + gb * 512 + e]));
    st_cv16(h1r + gb * 1024 + jp, f2bf(enc_h[(2 + dir) * 8192 + gb * 512 + e]));
  }

  const int sm = tid >> 5;
  const int skq = (tid & 31) * 8;

  {
    const u16* se = x0b + sm * 512;
#pragma unroll
    for (int jj = 0; jj < 2; ++jj)
      *(uint4*)&xe[sm * 520 + skq + jj * 256] = *(const uint4*)(se + skq + jj * 256);
  }
  gsyncf(++step, bar);

  for (int s = 0; s < 129; ++s) {
    const bool doA = (s < 128), doB = (s >= 1);

    uint4 rx[4], rh[4] = {}, re[2] = {};
    {
      const u16* sx = xr + (size_t)s * 16384 + sm * 1024;
#pragma unroll
      for (int jj = 0; jj < 4; ++jj) rx[jj] = *(const uint4*)(sx + skq + jj * 256);
      if (doB) {
        const u16* sh = h1r + (size_t)(s - 1) * 16384 + sm * 1024;
#pragma unroll
        for (int jj = 0; jj < 4; ++jj) rh[jj] = *(const uint4*)(sh + skq + jj * 256);
      }
      if (s < 127) {
        const u16* se = x0b + (size_t)(s + 1) * 8192 + sm * 512;
#pragma unroll
        for (int jj = 0; jj < 2; ++jj) re[jj] = *(const uint4*)(se + skq + jj * 256);
      }
    }
#pragma unroll
    for (int jj = 0; jj < 4; ++jj) *(uint4*)&xs[sm * 1032 + skq + jj * 256] = rx[jj];
    if (doB) {
#pragma unroll
      for (int jj = 0; jj < 4; ++jj) *(uint4*)&h1s[sm * 1032 + skq + jj * 256] = rh[jj];
    }
    __syncthreads();

    f32x4 acc0 = {0.f, 0.f, 0.f, 0.f}, acc1 = {0.f, 0.f, 0.f, 0.f};
    bool act0 = false, act1 = false;
    if (wave == 0) { if (doA) { BURST(acc0, xe, 520, 0, bw0) BURST(acc1, xe, 520, 0, bw1) act0 = act1 = true; } }
    else if (wave == 1) { if (doA) { BURST(acc0, xs, 1032, 0, bw0) BURST(acc1, xs, 1032, 0, bw1) act0 = act1 = true; } }
    else if (wave == 2) { if (doA) { BURST(acc0, xs, 1032, 512, bw0) BURST(acc1, xs, 1032, 512, bw1) act0 = act1 = true; } }
    else if (wave == 3) { if (doB) { BURST(acc0, xs, 1032, 0, bw0) BURST(acc1, xs, 1032, 0, bw1) act0 = act1 = true; } }
    else if (wave == 4) { if (doB) { BURST(acc0, xs, 1032, 512, bw0) BURST(acc1, xs, 1032, 512, bw1) act0 = act1 = true; } }
    else if (wave == 5) { if (doB) { BURST(acc0, h1s, 1032, 0, bw0) BURST(acc1, h1s, 1032, 0, bw1) act0 = act1 = true; } }
    else if (wave == 6) { if (doB) { BURST(acc0, h1s, 1032, 512, bw0) act0 = true; } }
    else { if (doB) { BURST(acc0, h1s, 1032, 512, bw0) act0 = true; } }
    if (act0) {
#pragma unroll
      for (int r = 0; r < 4; ++r) gls[q0][fr][(lane >> 4) * 4 + r] = acc0[r];
    }
    if (act1) {
#pragma unroll
      for (int r = 0; r < 4; ++r) gls[q0 + 1][fr][(lane >> 4) * 4 + r] = acc1[r];
    }
    __syncthreads();

    if (s < 127) {
#pragma unroll
      for (int jj = 0; jj < 2; ++jj) *(uint4*)&xe[sm * 520 + skq + jj * 256] = re[jj];
    }

    if (tid < 128) {
      const int jp = w8 + gdj;
      if (doA) {
        float gi = gls[0][gdj][gb] + gls[2][gdj][gb] + gls[4][gdj][gb] + cpA0;
        float gf = gls[0][8 + gdj][gb] + gls[2][8 + gdj][gb] + gls[4][8 + gdj][gb] + cpA1;
        float gg = gls[1][gdj][gb] + gls[3][gdj][gb] + gls[5][gdj][gb] + cpA2;
        float go = gls[1][8 + gdj][gb] + gls[3][8 + gdj][gb] + gls[5][8 + gdj][gb] + cpA3;
        c0r = sigf(gf) * c0r + sigf(gi) * tanh_(gg);
        float h = sigf(go) * tanh_(c0r);
        st_cv16(xr + (size_t)(s + 1) * 16384 + gb * 1024 + jp, f2bf(h));
      }
      if (doB) {
        float gi = gls[6][gdj][gb] + gls[8][gdj][gb] + gls[10][gdj][gb] +
                   gls[12][gdj][gb] + cpB0;
        float gf = gls[6][8 + gdj][gb] + gls[8][8 + gdj][gb] + gls[10][8 + gdj][gb] +
                   gls[12][8 + gdj][gb] + cpB1;
        float gg = gls[7][gdj][gb] + gls[9][gdj][gb] + gls[11][gdj][gb] +
                   gls[13][gdj][gb] + cpB2;
        float go = gls[7][8 + gdj][gb] + gls[9][8 + gdj][gb] + gls[11][8 + gdj][gb] +
                   gls[13][8 + gdj][gb] + cpB3;
        c1r = sigf(gf) * c1r + sigf(gi) * tanh_(gg);
        float h = sigf(go) * tanh_(c1r);
        st_cv16(h1r + (size_t)s * 16384 + gb * 1024 + jp, f2bf(h));
        out2b[((s - 1) * 16 + gb) * 1024 + jp] = f2bf(tanh_(h));
      }
    }
    gsyncf(++step, bar);
  }
}

// logits GEMM, B already bf16: A [2048][1024] bf16, Bwb [32000][1024] bf16.
__global__ __launch_bounds__(256, 2) void fc_gemm_bf(
    const u16* __restrict__ A, const u16* __restrict__ Bwb,
    const float* __restrict__ bias, float* __restrict__ C) {
  __shared__ __align__(16) u16 Al[128][40];
  __shared__ __align__(16) u16 Bl[128][40];

  const int tid = threadIdx.x;
  const int m0 = blockIdx.x * 128;
  const int n0 = blockIdx.y * 128;
  const int wave = tid >> 6;
  const int lane = tid & 63;
  const int wm = (wave & 1) * 64;
  const int wn = (wave >> 1) * 64;
  const int fr = lane & 15;
  const int ks = lane >> 4;
  const int srow = tid >> 1;
  const int sh16 = (tid & 1) * 16;

  const u16* Ag = A + (size_t)(m0 + srow) * 1024 + sh16;
  const u16* Bg = Bwb + (size_t)(n0 + srow) * 1024 + sh16;

  f32x4 acc[4][4] = {};

  for (int k0 = 0; k0 < 1024; k0 += 32) {
    uint4 a0 = *(const uint4*)(Ag + k0);
    uint4 a1 = *(const uint4*)(Ag + k0 + 8);
    uint4 b0 = *(const uint4*)(Bg + k0);
    uint4 b1 = *(const uint4*)(Bg + k0 + 8);

    __syncthreads();
    *(uint4*)&Al[srow][sh16] = a0;
    *(uint4*)&Al[srow][sh16 + 8] = a1;
    *(uint4*)&Bl[srow][sh16] = b0;
    *(uint4*)&Bl[srow][sh16 + 8] = b1;
    __syncthreads();

    bf16x8 af[4], bf[4];
#pragma unroll
    for (int i = 0; i < 4; ++i) af[i] = *(const bf16x8*)&Al[wm + i * 16 + fr][ks * 8];
#pragma unroll
    for (int j = 0; j < 4; ++j) bf[j] = *(const bf16x8*)&Bl[wn + j * 16 + fr][ks * 8];
#pragma unroll
    for (int i = 0; i < 4; ++i)
#pragma unroll
      for (int j = 0; j < 4; ++j)
        acc[i][j] = __builtin_amdgcn_mfma_f32_16x16x32_bf16(af[i], bf[j], acc[i][j], 0, 0, 0);
  }

  float bj[4];
#pragma unroll
  for (int j = 0; j < 4; ++j) bj[j] = bias[n0 + wn + j * 16 + fr];

  const int mrb = (lane >> 4) * 4;
#pragma unroll
  for (int i = 0; i < 4; ++i) {
#pragma unroll
    for (int r = 0; r < 4; ++r) {
      const int m = m0 + wm + i * 16 + mrb + r;
      float* dst = C + ((size_t)(m & 15) * 128 + (m >> 4)) * 32000;
#pragma unroll
      for (int j = 0; j < 4; ++j) {
        dst[n0 + wn + j * 16 + fr] = acc[i][j][r] + bj[j];
      }
    }
  }
}

// fallback fc (fp32 B, converts per tile) — used if ws too small for fcwb.
__global__ __launch_bounds__(256, 2) void fc_gemm_mfma(
    const u16* __restrict__ A, const float* __restrict__ Bw,
    const float* __restrict__ bias, float* __restrict__ C) {
  __shared__ __align__(16) u16 Al[128][40];
  __shared__ __align__(16) u16 Bl[128][40];
  const int tid = threadIdx.x;
  const int m0 = blockIdx.x * 128;
  const int n0 = blockIdx.y * 128;
  const int wave = tid >> 6;
  const int lane = tid & 63;
  const int wm = (wave & 1) * 64;
  const int wn = (wave >> 1) * 64;
  const int fr = lane & 15;
  const int ks = lane >> 4;
  const int srow = tid >> 1;
  const int sh16 = (tid & 1) * 16;
  const u16* Ag = A + (size_t)(m0 + srow) * 1024 + sh16;
  const float* Bg = Bw + (size_t)(n0 + srow) * 1024 + sh16;
  f32x4 acc[4][4] = {};
  for (int k0 = 0; k0 < 1024; k0 += 32) {
    uint4 a0 = *(const uint4*)(Ag + k0);
    uint4 a1 = *(const uint4*)(Ag + k0 + 8);
    float bfv[16];
    *(float4*)&bfv[0] = *(const float4*)(Bg + k0);
    *(float4*)&bfv[4] = *(const float4*)(Bg + k0 + 4);
    *(float4*)&bfv[8] = *(const float4*)(Bg + k0 + 8);
    *(float4*)&bfv[12] = *(const float4*)(Bg + k0 + 12);
    u16 bu[16];
#pragma unroll
    for (int u = 0; u < 16; ++u) bu[u] = f2bf(bfv[u]);
    __syncthreads();
    *(uint4*)&Al[srow][sh16] = a0;
    *(uint4*)&Al[srow][sh16 + 8] = a1;
    *(uint4*)&Bl[srow][sh16] = *(uint4*)&bu[0];
    *(uint4*)&Bl[srow][sh16 + 8] = *(uint4*)&bu[8];
    __syncthreads();
    bf16x8 af[4], bf[4];
#pragma unroll
    for (int i = 0; i < 4; ++i) af[i] = *(const bf16x8*)&Al[wm + i * 16 + fr][ks * 8];
#pragma unroll
    for (int j = 0; j < 4; ++j) bf[j] = *(const bf16x8*)&Bl[wn + j * 16 + fr][ks * 8];
#pragma unroll
    for (int i = 0; i < 4; ++i)
#pragma unroll
      for (int j = 0; j < 4; ++j)
        acc[i][j] = __builtin_amdgcn_mfma_f32_16x16x32_bf16(af[i], bf[j], acc[i][j], 0, 0, 0);
  }
  float bj[4];
#pragma unroll
  for (int j = 0; j < 4; ++j) bj[j] = bias[n0 + wn + j * 16 + fr];
  const int mrb = (lane >> 4) * 4;
#pragma unroll
  for (int i = 0; i < 4; ++i) {
#pragma unroll
    for (int r = 0; r < 4; ++r) {
      const int m = m0 + wm + i * 16 + mrb + r;
      float* dst = C + ((size_t)(m & 15) * 128 + (m >> 4)) * 32000;
#pragma unroll
      for (int j = 0; j < 4; ++j) dst[n0 + wn + j * 16 + fr] = acc[i][j][r] + bj[j];
    }
  }
}

extern "C" void kernel_launch(void* const* d_in, const int* in_sizes, int n_in,
                              void* d_out, int out_size, void* d_ws, size_t ws_size,
                              hipStream_t stream) {
  const float* enc_h = (const float*)d_in[0];
  const float* enc_c = (const float*)d_in[1];
  const int* tgt = (const int*)d_in[2];
  const float* emb = (const float*)d_in[3];
  const float* wih0 = (const float*)d_in[4];
  const float* whh0 = (const float*)d_in[5];
  const float* bih0 = (const float*)d_in[6];
  const float* bhh0 = (const float*)d_in[7];
  const float* wih1 = (const float*)d_in[8];
  const float* whh1 = (const float*)d_in[9];
  const float* bih1 = (const float*)d_in[10];
  const float* bhh1 = (const float*)d_in[11];
  const float* fcw = (const float*)d_in[12];
  const float* fcb = (const float*)d_in[13];
  float* logits = (float*)d_out;

  unsigned* bar = (unsigned*)d_ws;  // 32 KB barrier region (flags @128B stride)
  hipMemsetAsync(d_ws, 0, 32768, stream);

  // ws layout: bar 32K | cp 256K | x0b 2M | xr 4.125M | h1r 4.125M |
  //            out2b 4M | fcwb 65.5M  (total ~80.6 MB)
  float* cp = (float*)((char*)d_ws + 32768);
  u16* x0b = (u16*)(cp + 65536);
  u16* xr = x0b + 1048576;
  u16* h1r = xr + 2113536;
  u16* out2b = h1r + 2113536;
  u16* fcwb = out2b + 2097152;
  const bool use_bf_fc = (ws_size >= 80576512ull);

  prep_emb<<<512, 256, 0, stream>>>(tgt, emb, x0b);
  prep_ctx2<<<256, 256, 0, stream>>>(enc_h, wih0, cp);
  if (use_bf_fc)
    prep_bf16<<<2048, 256, 0, stream>>>(fcw, fcwb, 4096000);
  dec_seq_rw2<<<NBLK, 512, 0, stream>>>(enc_h, enc_c, wih0, whh0, wih1, whh1,
                                        bih0, bhh0, bih1, bhh1, cp, x0b,
                                        xr, h1r, out2b, bar);
  if (use_bf_fc)
    fc_gemm_bf<<<dim3(16, 250), 256, 0, stream>>>(out2b, fcwb, fcb, logits);
  else
    fc_gemm_mfma<<<dim3(16, 250), 256, 0, stream>>>(out2b, fcw, fcb, logits);
}